// Round 10
// baseline (3872.736 us; speedup 1.0000x reference)
//
#include <hip/hip_runtime.h>

// ---------------- problem constants ----------------
#define NB 8          // meta-batch (tasks)
#define NT 5          // inner steps
#define NL 16         // test examples per task
#define NCLS 100
#define FEAT 4096
#define CHW (3*64*64) // 12288

// per-task fast-weight block offsets (floats)
#define OFF_W0 0
#define OFF_B0 864
#define OFF_W1 896
#define OFF_B1 19328
#define OFF_W2 19392
#define OFF_B2 93120
#define OFF_W3 93248
#define OFF_B3 388160
#define OFF_W4 388416
#define OFF_B4 978240
#define OFF_WO 978496
#define OFF_BO 1388096
#define PT     1388196   // floats per task

// per-task inner activation block offsets (floats)
#define A1 0          // 32*64*64 = 131072
#define A2 131072     // 64*32*32 =  65536
#define A3 196608     // 128*16*16 = 32768
#define A4 229376     // 256*8*8  =  16384
#define A5 245760     // 256*4*4  =   4096
#define ATOT 249856

struct Params12 { const float* p[12]; };

// r22: bijective XCD swizzle (T1/m204).
__device__ __forceinline__ int xcd_swz(int b, int cpx) {
    return (b & 7) * cpx + (b >> 3);
}

// ---------------- broadcast initial params to per-task fast weights ----------------
__global__ void bcast_kernel(Params12 ps, float* __restrict__ fw) {
    const int offs[13] = {OFF_W0,OFF_B0,OFF_W1,OFF_B1,OFF_W2,OFF_B2,OFF_W3,OFF_B3,
                          OFF_W4,OFF_B4,OFF_WO,OFF_BO,PT};
    long idx = (long)blockIdx.x * blockDim.x + threadIdx.x;
    long total = (long)NB * PT;
    if (idx >= total) return;
    int i = (int)(idx % PT);
    int j = 11;
    while (j > 0 && i < offs[j]) --j;
    fw[idx] = ps.p[j][i - offs[j]];
}

// ---------------- train-path conv: conv_fwd mapping + UF-blocked loads (proven r7) ----------------
template<int IC,int IH,int IW,int OC,int OH,int OW,int S,int UF,int BS>
__global__ __launch_bounds__(BS) void conv_fwd_u(
    const float* __restrict__ xb, long x_ts,
    const float* __restrict__ fw, int woff, int boff,
    float* __restrict__ yb, long y_ts)
{
    constexpr int OHW = OH*OW, IHW = IH*IW;
    long idx = (long)blockIdx.x * BS + threadIdx.x;
    int pix = (int)(idx % OHW); long r = idx / OHW;
    int oc = (int)(r % OC); int b = (int)(r / OC);
    int oh = pix / OW, ow = pix % OW;
    int ih0 = oh*S - 1, iw0 = ow*S - 1;

    const float* x = xb + (long)b * x_ts;
    const float* w = fw + (long)b * PT + woff + (long)oc * IC * 9;
    float acc = fw[(long)b * PT + boff + oc];

    #pragma unroll 1
    for (int ic0 = 0; ic0 < IC; ic0 += UF) {
        float xv[UF][9];
        #pragma unroll
        for (int u = 0; u < UF; ++u) {
            const float* xc = x + (long)(ic0 + u) * IHW;
            #pragma unroll
            for (int kh = 0; kh < 3; ++kh) {
                int ih = ih0 + kh;
                #pragma unroll
                for (int kw = 0; kw < 3; ++kw) {
                    int iw = iw0 + kw;
                    bool v = ((unsigned)ih < (unsigned)IH) && ((unsigned)iw < (unsigned)IW);
                    xv[u][kh*3+kw] = v ? xc[ih*IW + iw] : 0.f;
                }
            }
        }
        #pragma unroll
        for (int u = 0; u < UF; ++u) {
            const float* wc = w + (ic0 + u) * 9;
            #pragma unroll
            for (int k = 0; k < 9; ++k)
                acc += xv[u][k] * wc[k];
        }
    }
    yb[(long)b * y_ts + (long)oc * OHW + pix] = fmaxf(acc, 0.f);
}

// ---------------- r16/r22: IC-split train conv (L4) + XCD swizzle ----------------
template<int IC,int IH,int IW,int OC,int OH,int OW,int S,int UF,int BS,int KS>
__global__ __launch_bounds__(BS) void conv_fwd_uks(
    const float* __restrict__ xb, long x_ts,
    const float* __restrict__ fw, int woff,
    float* __restrict__ pb)
{
    constexpr int OHW = OH*OW, IHW = IH*IW;
    constexpr int ICC = IC/KS;
    constexpr int GRID = (NB*KS*OC*OHW)/BS;
    static_assert((NB*KS*OC*OH*OW) % (BS*8) == 0, "xcd swizzle needs grid%8==0");
    int sb = xcd_swz(blockIdx.x, GRID >> 3);
    long idx = (long)sb * BS + threadIdx.x;
    int pix = (int)(idx % OHW); long r = idx / OHW;
    int oc = (int)(r % OC); r /= OC;
    int ks = (int)(r % KS); int b = (int)(r / KS);
    int oh = pix / OW, ow = pix % OW;
    int ih0 = oh*S - 1, iw0 = ow*S - 1;

    const float* x = xb + (long)b * x_ts;
    const float* w = fw + (long)b * PT + woff + (long)oc * IC * 9;
    float acc = 0.f;

    #pragma unroll 1
    for (int ic0 = ks*ICC; ic0 < (ks+1)*ICC; ic0 += UF) {
        float xv[UF][9];
        #pragma unroll
        for (int u = 0; u < UF; ++u) {
            const float* xc = x + (long)(ic0 + u) * IHW;
            #pragma unroll
            for (int kh = 0; kh < 3; ++kh) {
                int ih = ih0 + kh;
                #pragma unroll
                for (int kw = 0; kw < 3; ++kw) {
                    int iw = iw0 + kw;
                    bool v = ((unsigned)ih < (unsigned)IH) && ((unsigned)iw < (unsigned)IW);
                    xv[u][kh*3+kw] = v ? xc[ih*IW + iw] : 0.f;
                }
            }
        }
        #pragma unroll
        for (int u = 0; u < UF; ++u) {
            const float* wc = w + (ic0 + u) * 9;
            #pragma unroll
            for (int k = 0; k < 9; ++k)
                acc += xv[u][k] * wc[k];
        }
    }
    pb[((long)ks*NB + b) * ((long)OC*OHW) + (long)oc*OHW + pix] = acc;
}

// ---------------- r17/r22: oc-uniform scalar-weight train conv (L3) + XCD swizzle ----------------
template<int IC,int IH,int IW,int OC,int OH,int OW,int S,int UF,int KS>
__global__ __launch_bounds__(64) void conv_fwd_us(
    const float* __restrict__ xb, long x_ts,
    const float* __restrict__ fw, int woff,
    float* __restrict__ pb)
{
    constexpr int OHW = OH*OW, IHW = IH*IW, ICC = IC/KS;
    static_assert(OHW == 64, "one wave = one oc-plane");
    constexpr int GRID = OC*KS*NB;
    static_assert(GRID % 8 == 0, "xcd swizzle needs grid%8==0");
    int bi = xcd_swz(blockIdx.x, GRID >> 3);
    int oc = bi % OC; int ks = (bi / OC) % KS; int b = bi / (OC*KS);
    int pix = threadIdx.x;
    int oh = pix / OW, ow = pix % OW;
    int ih0 = oh*S - 1, iw0 = ow*S - 1;

    const float* x = xb + (long)b * x_ts;
    const float* w = fw + (long)b * PT + woff + (long)oc * IC * 9;  // uniform

    float acc = 0.f;
    #pragma unroll 1
    for (int ic0 = ks*ICC; ic0 < (ks+1)*ICC; ic0 += UF) {
        float xv[UF][9];
        #pragma unroll
        for (int u = 0; u < UF; ++u) {
            const float* xc = x + (long)(ic0 + u) * IHW;
            #pragma unroll
            for (int kh = 0; kh < 3; ++kh) {
                int ih = ih0 + kh;
                #pragma unroll
                for (int kw = 0; kw < 3; ++kw) {
                    int iw = iw0 + kw;
                    bool v = ((unsigned)ih < (unsigned)IH) && ((unsigned)iw < (unsigned)IW);
                    xv[u][kh*3+kw] = v ? xc[ih*IW + iw] : 0.f;
                }
            }
        }
        #pragma unroll
        for (int u = 0; u < UF; ++u) {
            const float* wc = w + (ic0 + u) * 9;
            #pragma unroll
            for (int k = 0; k < 9; ++k)
                acc += xv[u][k] * wc[k];
        }
    }
    pb[((long)ks*NB + b) * ((long)OC*OHW) + (long)oc*OHW + pix] = acc;
}

// ---------------- tiled conv fwd (test path L0 + fallback path) — proven r5 ----------------
template<int IC,int IH,int IW,int OC,int OH,int OW,int S,int TOC,int NSUB,int ICB>
__global__ __launch_bounds__(256) void conv_fwd2(
    const float* __restrict__ xb, long x_ts, long x_es,
    const float* __restrict__ fw, int woff, int boff,
    float* __restrict__ yb, long y_ts, int N)
{
    constexpr int OHW = OH*OW, IHW = IH*IW;
    constexpr int PPB = 256/NSUB;
    constexpr int TILES = OHW/PPB;
    constexpr int OCB = NSUB*TOC;
    constexpr int NOCG = OC/OCB;
    __shared__ float wlds[ICB*9*OCB];

    int bi = blockIdx.x;
    int tile = bi % TILES;
    int ocg  = (bi / TILES) % NOCG;
    int n    = (bi / (TILES*NOCG)) % N;
    int b    = bi / (TILES*NOCG*N);

    int tid = threadIdx.x;
    int pixl = tid % PPB, sub = tid / PPB;
    int pix = tile * PPB + pixl;
    int oc0 = ocg * OCB + sub * TOC;
    int oh = pix / OW, ow = pix % OW;
    int ih0 = oh*S - 1, iw0 = ow*S - 1;

    const float* xp  = xb + (long)b * x_ts + (long)n * x_es;
    const float* fwp = fw + (long)b * PT + woff;
    const float* bp  = fw + (long)b * PT + boff;

    float acc[TOC];
    #pragma unroll
    for (int t = 0; t < TOC; ++t) acc[t] = bp[oc0 + t];

    #pragma unroll 1
    for (int ic0i = 0; ic0i < IC; ic0i += ICB) {
        __syncthreads();
        for (int i = tid; i < ICB*9*OCB; i += 256) {
            int o = i % OCB; int rem = i / OCB; int k = rem % 9; int icb = rem / 9;
            wlds[i] = fwp[((long)(ocg*OCB + o) * IC + ic0i + icb) * 9 + k];
        }
        __syncthreads();
        #pragma unroll 2
        for (int icb = 0; icb < ICB; ++icb) {
            const float* xc = xp + (long)(ic0i + icb) * IHW;
            float xv[9];
            #pragma unroll
            for (int kh = 0; kh < 3; ++kh)
            #pragma unroll
            for (int kw = 0; kw < 3; ++kw) {
                int ih = ih0 + kh, iw = iw0 + kw;
                bool v = ((unsigned)ih < (unsigned)IH) && ((unsigned)iw < (unsigned)IW);
                xv[kh*3+kw] = v ? xc[ih*IW + iw] : 0.f;
            }
            const float* wl = wlds + icb*9*OCB + sub*TOC;
            #pragma unroll
            for (int k = 0; k < 9; ++k) {
                #pragma unroll
                for (int t = 0; t < TOC; ++t)
                    acc[t] += xv[k] * wl[k*OCB + t];
            }
        }
    }

    float* yp = yb + (long)b * y_ts;
    #pragma unroll
    for (int t = 0; t < TOC; ++t)
        yp[((long)n*OC + oc0 + t) * OHW + pix] = fmaxf(acc[t], 0.f);
}

// ---------------- r23: gx with phase-split LDS (bank-conflict-free stride-2 reads) ----------------
// r22 left SQ_LDS_BANK_CONFLICT=1.02e7/dispatch: stride-2 reads xr[pcol*2+kw] hit only
// EVEN banks (row stride 66 = 2 mod 32) -> 4-way conflicts on all 9 ds_reads per ic.
// Fix: store even padded-cols at [0..HALF), odd at [HALF..PW) -> reads become pcol /
// HALF+pcol / pcol+1 (lane-stride 1); row stride RS with 2*RS = OW (mod 32) tiles the
// banks across prow groups (2 lanes/bank = free). Pure LDS permutation: bit-identical.
template<int IC,int IH,int IW,int OC,int OH,int OW,int S,
         int NG,int TH,int ICB,int KS,int NTOT,int TOCP>
__global__ __launch_bounds__(256, 8) void conv_fwd_gx(
    const float* __restrict__ xb, long x_ts, long x_es,
    const float* __restrict__ fw, int woff, int boff,
    float* __restrict__ yb, long y_ts,          // used when KS==1
    float* __restrict__ pb)                     // used when KS>1
{
    constexpr int OHW = OH*OW, IHW = IH*IW;
    constexpr int OCB2 = 4*TOCP;
    constexpr int NOCG = OC/OCB2;
    constexpr int RT = OH/TH;
    constexpr int NGRP = NTOT/NG;
    constexpr int ICC = IC/KS;
    constexpr int PW = IW + 1;                  // left zero-border only (S==2)
    constexpr int HALF = (PW + 1)/2;            // even-phase slot count
    constexpr int TGT = (OW >= 32) ? (PW % 16) : ((OW/2) % 16);
    constexpr int RS = PW + ((TGT - (PW % 16) + 16) % 16);   // bank-tiling row stride
    constexpr int PROWS = (TH-1)*S + 3;         // rows incl. top border + halo
    constexpr int XP = (PROWS*RS) | 1;          // odd plane stride
    constexpr int GRID = NOCG*RT*NGRP*KS*NB;
    static_assert(GRID % 8 == 0, "xcd swizzle needs grid%8==0");
    static_assert(NG*TH*OW == 64, "lanes must cover exactly 64 pixels");
    static_assert(S == 2, "padding derivation assumes stride 2");
    static_assert(ICC % ICB == 0, "chunking");

    __shared__ float xs[NG*ICB*XP];

    int bi = xcd_swz(blockIdx.x, GRID >> 3);
    int ocg = bi % NOCG;
    int rt  = (bi / NOCG) % RT;
    int ng  = (bi / (NOCG*RT)) % NGRP;
    int ks  = (bi / (NOCG*RT*NGRP)) % KS;
    int b   = bi / (NOCG*RT*NGRP*KS);

    int tid = threadIdx.x;
    int pl = tid & 63;
    int ocsub = __builtin_amdgcn_readfirstlane(tid >> 6);   // wave-uniform -> SGPR
    int nl = pl / (TH*OW);
    int prow = (pl / OW) % TH;
    int pcol = pl % OW;
    int oc0 = ocg*OCB2 + ocsub*TOCP;                         // uniform

    const float* xbb = xb + (long)b * x_ts + (long)(ng*NG) * x_es;
    const float* wb  = fw + (long)b * PT + woff;             // uniform base

    float acc[TOCP];
    #pragma unroll
    for (int t = 0; t < TOCP; ++t)
        acc[t] = (KS == 1) ? fw[(long)b*PT + boff + oc0 + t] : 0.f;

    const int ih0t = rt*TH*S - 1;

    #pragma unroll 1
    for (int c = 0; c < ICC/ICB; ++c) {
        int ic0 = ks*ICC + c*ICB;
        if (c) __syncthreads();
        // stage padded x tile (phase-split columns, coalesced global row reads)
        for (int i = tid; i < NG*ICB*PROWS*PW; i += 256) {
            int cc = i % PW;
            int r  = (i / PW) % PROWS;
            int icb = (i / (PW*PROWS)) % ICB;
            int nl2 = i / (PW*PROWS*ICB);
            int ih = ih0t + r, iw = cc - 1;
            float v = 0.f;
            if (ih >= 0 && iw >= 0)
                v = xbb[(long)nl2 * x_es + (long)(ic0+icb)*IHW + ih*IW + iw];
            int cp = (cc & 1) ? (HALF + (cc >> 1)) : (cc >> 1);
            xs[(nl2*ICB + icb)*XP + r*RS + cp] = v;
        }
        __syncthreads();
        #pragma unroll 2
        for (int icb = 0; icb < ICB; ++icb) {
            int ic = ic0 + icb;
            const float* xr = xs + (nl*ICB + icb)*XP + (prow*S)*RS;
            float xv[9];
            #pragma unroll
            for (int kh = 0; kh < 3; ++kh) {
                xv[kh*3+0] = xr[kh*RS + pcol];          // c=2*pcol   (even phase)
                xv[kh*3+1] = xr[kh*RS + HALF + pcol];   // c=2*pcol+1 (odd phase)
                xv[kh*3+2] = xr[kh*RS + pcol + 1];      // c=2*pcol+2 (even phase)
            }
            const float* wr = wb + ((long)oc0*IC + ic)*9;     // uniform
            #pragma unroll
            for (int t = 0; t < TOCP; ++t) {
                const float* wt = wr + (long)t*IC*9;          // uniform
                #pragma unroll
                for (int k = 0; k < 9; ++k)
                    acc[t] += xv[k] * wt[k];
            }
        }
    }

    int n = ng*NG + nl;
    int pix = (rt*TH + prow)*OW + pcol;
    if (KS == 1) {
        float* yp = yb + (long)b * y_ts;
        #pragma unroll
        for (int t = 0; t < TOCP; ++t)
            yp[((long)n*OC + oc0 + t)*OHW + pix] = fmaxf(acc[t], 0.f);
    } else {
        float* yp = pb + ((long)ks*NB + b) * ((long)NTOT*OC*OHW);
        #pragma unroll
        for (int t = 0; t < TOCP; ++t)
            yp[((long)n*OC + oc0 + t)*OHW + pix] = acc[t];
    }
}

// ---------------- r14: deterministic KS-partial reduce + bias + relu ----------------
template<int KS>
__global__ __launch_bounds__(256) void ksum_relu(
    const float* __restrict__ pb, const float* __restrict__ fw, int boff,
    float* __restrict__ yb, long y_ts, int N, int OC, int OHW)
{
    long plane = (long)N * OC * OHW;
    long idx = (long)blockIdx.x * 256 + threadIdx.x;
    long total = (long)NB * plane;
    if (idx >= total) return;
    int b = (int)(idx / plane);
    long rem = idx % plane;
    int oc = (int)((rem / OHW) % OC);
    float s = fw[(long)b * PT + boff + oc];
    #pragma unroll
    for (int ks = 0; ks < KS; ++ks)
        s += pb[((long)ks * NB + b) * plane + rem];
    yb[(long)b * y_ts + rem] = fmaxf(s, 0.f);
}

// ---------------- r15: GEMM-tiled conv dW+db (train path, deep layers) ----------------
template<int IC,int IH,int IW,int OC,int OH,int OW,int S,int OCT,int ICT,int OCPT,int OHC>
__global__ __launch_bounds__(256) void conv_bwd_dwg(
    float* __restrict__ fw, int woff, int boff,
    const float* __restrict__ dzbuf, int dz_off,
    const float* __restrict__ xb, long x_ts,
    const float* __restrict__ loglr)
{
    constexpr int OHW = OH*OW, IHW = IH*IW;
    constexpr int IW2 = IW + 2;
    constexpr int RW  = OHC*S + 1;
    constexpr int XPRAW = RW * IW2;
    constexpr int XP = XPRAW | 1;
    constexpr int OHWC = OHC*OW;
    constexpr int DZP = OHWC + 1;
    constexpr int NCH = OH/OHC;
    constexpr int OCSL = OCT/OCPT;
    static_assert(OCSL*ICT == 256, "block must be 256 threads");
    static_assert((OW & (OW-1)) == 0, "OW power of two");
    constexpr int LOG_OW = (OW==4) ? 2 : ((OW==8) ? 3 : 4);
    constexpr int NOCG = OC/OCT, NICG = IC/ICT;

    __shared__ float dzs[OCT*DZP];
    __shared__ float xs[ICT*XP];

    int bi = blockIdx.x;
    int icg = bi % NICG;
    int ocg = (bi / NICG) % NOCG;
    int b   = bi / (NICG*NOCG);
    int oc0 = ocg*OCT, ic0 = icg*ICT;

    int tid = threadIdx.x;
    int ic_sub = tid % ICT;
    int oc_sub = tid / ICT;

    const float* dzp = dzbuf + (long)b*ATOT + dz_off + (long)oc0*OHW;
    const float* xp  = xb + (long)b*x_ts + (long)ic0*IHW;

    float acc[OCPT][9];
    float accb[OCPT];
    #pragma unroll
    for (int p = 0; p < OCPT; ++p) {
        accb[p] = 0.f;
        #pragma unroll
        for (int k = 0; k < 9; ++k) acc[p][k] = 0.f;
    }

    for (int c = 0; c < NCH; ++c) {
        if (c) __syncthreads();
        for (int i = tid; i < OCT*OHWC; i += 256) {
            int oc = i / OHWC, j = i % OHWC;
            dzs[oc*DZP + j] = dzp[(long)oc*OHW + c*OHWC + j];
        }
        for (int i = tid; i < ICT*XPRAW; i += 256) {
            int ic = i / XPRAW, j = i % XPRAW;
            int r = j / IW2, col = j % IW2;
            int ih = c*(OHC*S) - 1 + r;
            int iw = col - 1;
            float v = 0.f;
            if ((unsigned)ih < (unsigned)IH && (unsigned)iw < (unsigned)IW)
                v = xp[(long)ic*IHW + ih*IW + iw];
            xs[ic*XP + j] = v;
        }
        __syncthreads();

        const float* dzr = dzs + oc_sub*DZP;
        const float* xr0 = xs + ic_sub*XP;
        #pragma unroll 2
        for (int pos = 0; pos < OHWC; ++pos) {
            int ohl = pos >> LOG_OW;
            int ow  = pos & (OW-1);
            const float* xr = xr0 + (ohl*S)*IW2 + ow*S;
            float xv[9];
            #pragma unroll
            for (int kh = 0; kh < 3; ++kh)
                #pragma unroll
                for (int kw = 0; kw < 3; ++kw)
                    xv[kh*3+kw] = xr[kh*IW2 + kw];
            #pragma unroll
            for (int p = 0; p < OCPT; ++p) {
                float dzv = dzr[p*OCSL*DZP + pos];
                accb[p] += dzv;
                #pragma unroll
                for (int k = 0; k < 9; ++k) acc[p][k] += dzv * xv[k];
            }
        }
    }

    float lr = expf(loglr[0]);
    #pragma unroll
    for (int p = 0; p < OCPT; ++p) {
        int oc = oc0 + p*OCSL + oc_sub;
        float* wp = fw + (long)b*PT + woff + ((long)oc*IC + ic0 + ic_sub)*9;
        #pragma unroll
        for (int k = 0; k < 9; ++k) wp[k] -= lr * acc[p][k];
        if (ic_sub == 0 && icg == 0)
            fw[(long)b*PT + boff + oc] -= lr * accb[p];
    }
}

// ---------------- head forward ----------------
__global__ void head_fwd(const float* __restrict__ a5b, long a_ts, long a_es,
                         const float* __restrict__ gb, long g_ts, long g_es,
                         const float* __restrict__ fw,
                         float* __restrict__ ob, long o_ts, long o_es, int N)
{
    int wid = (int)(((long)blockIdx.x * blockDim.x + threadIdx.x) >> 6);
    int lane = threadIdx.x & 63;
    int total = NB * N * NCLS;
    if (wid >= total) return;
    int cls = wid % NCLS; int r = wid / NCLS;
    int n = r % N; int b = r / N;
    const float* a5 = a5b + (long)b * a_ts + (long)n * a_es;
    const float* g  = gb  + (long)b * g_ts + (long)n * g_es;
    const float* W  = fw + (long)b * PT + OFF_WO + (long)cls * FEAT;
    float acc = 0.f;
    for (int m = lane; m < FEAT; m += 64) acc += W[m] * a5[m] * g[m];
    for (int off = 32; off; off >>= 1) acc += __shfl_down(acc, off, 64);
    if (lane == 0)
        ob[(long)b * o_ts + (long)n * o_es + cls] = acc + fw[(long)b * PT + OFF_BO + cls];
}

// ---------------- inner softmax -> dlogit ----------------
__global__ void softmax_dlogit(const float* __restrict__ logi, const int* __restrict__ ty, int t,
                               float* __restrict__ dlog)
{
    __shared__ float red[128];
    int b = blockIdx.x, tid = threadIdx.x;
    const float* lo = logi + b * NCLS;
    float v = (tid < NCLS) ? lo[tid] : -1e30f;
    red[tid] = v; __syncthreads();
    for (int s2 = 64; s2; s2 >>= 1) { if (tid < s2) red[tid] = fmaxf(red[tid], red[tid + s2]); __syncthreads(); }
    float mx = red[0]; __syncthreads();
    float e = (tid < NCLS) ? expf(v - mx) : 0.f;
    red[tid] = e; __syncthreads();
    for (int s2 = 64; s2; s2 >>= 1) { if (tid < s2) red[tid] += red[tid + s2]; __syncthreads(); }
    float sum = red[0];
    if (tid < NCLS) {
        int y = ty[b * NT + t];
        dlog[b * NCLS + tid] = e / sum - (tid == y ? 1.f : 0.f);
    }
}

// ---------------- head backward: dz5 ----------------
__global__ void head_bwd_dz5(const float* __restrict__ fw, const float* __restrict__ dlog,
                             const float* __restrict__ ain, const float* __restrict__ gb, long g_ts,
                             float* __restrict__ dz)
{
    int idx = blockIdx.x * blockDim.x + threadIdx.x;
    if (idx >= NB * FEAT) return;
    int m = idx % FEAT, b = idx / FEAT;
    const float* W = fw + (long)b * PT + OFF_WO;
    float df = 0.f;
    for (int c = 0; c < NCLS; ++c) df += W[(long)c * FEAT + m] * dlog[b * NCLS + c];
    float a = ain[(long)b * ATOT + A5 + m];
    dz[(long)b * ATOT + A5 + m] = (a > 0.f) ? df * gb[(long)b * g_ts + m] : 0.f;
}

// ---------------- head update ----------------
__global__ void head_update(float* __restrict__ fw, const float* __restrict__ dlog,
                            const float* __restrict__ ain, const float* __restrict__ gb, long g_ts,
                            const float* __restrict__ loglr)
{
    long idx = (long)blockIdx.x * blockDim.x + threadIdx.x;
    long total = (long)NB * NCLS * FEAT;
    if (idx >= total) return;
    int m = (int)(idx % FEAT); long r = idx / FEAT;
    int c = (int)(r % NCLS); int b = (int)(r / NCLS);
    float lr = expf(loglr[0]);
    float f = ain[(long)b * ATOT + A5 + m] * gb[(long)b * g_ts + m];
    float dl = dlog[b * NCLS + c];
    fw[(long)b * PT + OFF_WO + (long)c * FEAT + m] -= lr * dl * f;
    if (m == 0) fw[(long)b * PT + OFF_BO + c] -= lr * dl;
}

// ---------------- conv backward dX (stride-2, parity taps, LDS weights) — r9 exact (kept for L1) ----------------
template<int IC,int IH,int IW,int OC,int OH,int OW,int ICG,int BLK>
__global__ __launch_bounds__(BLK) void conv_bwd_dx2(
    const float* __restrict__ dzbuf, int dz_off,
    const float* __restrict__ fw, int woff,
    const float* __restrict__ ain, int ain_off,
    float* __restrict__ dzin, int dzin_off)
{
    constexpr int IHW = IH*IW, OHW = OH*OW, NICG = IC/ICG, PB = IHW/BLK;
    __shared__ float wlds[OC*9*ICG];
    int bi = blockIdx.x;
    int pb  = bi % PB;
    int icg = (bi / PB) % NICG;
    int b   = bi / (PB * NICG);
    int ic0 = icg * ICG;
    const float* fwp = fw + (long)b * PT + woff;
    for (int i = threadIdx.x; i < OC*9*ICG; i += BLK) {
        int g = i % ICG; int rem = i / ICG; int k = rem % 9; int oc = rem / 9;
        wlds[i] = fwp[((long)oc * IC + ic0 + g) * 9 + k];
    }
    __syncthreads();

    int pix = pb * BLK + threadIdx.x;
    int ih = pix / IW, iw = pix % IW;
    int kh0 = (ih + 1) & 1, kw0 = (iw + 1) & 1;
    int ohA = (ih + 1 - kh0) >> 1, owA = (iw + 1 - kw0) >> 1;
    float mhA = (ohA < OH) ? 1.f : 0.f;   float mhB = (kh0 == 0) ? 1.f : 0.f;
    float mwA = (owA < OW) ? 1.f : 0.f;   float mwB = (kw0 == 0) ? 1.f : 0.f;
    int ohB = ohA - 1, owB = owA - 1;
    int ohAc = (ohA < OH) ? ohA : 0;  int owAc = (owA < OW) ? owA : 0;
    int ohBc = (ohB >= 0) ? ohB : 0;  int owBc = (owB >= 0) ? owB : 0;

    int oAA = ohAc*OW + owAc; float mAA = mhA*mwA; int kAA = kh0*3 + kw0;
    int oAB = ohAc*OW + owBc; float mAB = mhA*mwB; int kAB = kh0*3 + kw0 + 2;
    int oBA = ohBc*OW + owAc; float mBA = mhB*mwA; int kBA = (kh0+2)*3 + kw0;
    int oBB = ohBc*OW + owBc; float mBB = mhB*mwB; int kBB = (kh0+2)*3 + kw0 + 2;

    const float* dzp = dzbuf + (long)b * ATOT + dz_off;
    float acc[ICG];
    #pragma unroll
    for (int g = 0; g < ICG; ++g) acc[g] = 0.f;

    for (int oc = 0; oc < OC; ++oc) {
        const float* dzo = dzp + oc * OHW;
        float dAA = dzo[oAA] * mAA;
        float dAB = dzo[oAB] * mAB;
        float dBA = dzo[oBA] * mBA;
        float dBB = dzo[oBB] * mBB;
        const float* w = wlds + oc * 9 * ICG;
        #pragma unroll
        for (int g = 0; g < ICG; ++g)
            acc[g] += dAA * w[kAA*ICG+g] + dAB * w[kAB*ICG+g]
                    + dBA * w[kBA*ICG+g] + dBB * w[kBB*ICG+g];
    }
    #pragma unroll
    for (int g = 0; g < ICG; ++g) {
        long p = (long)b * ATOT + (long)(ic0 + g) * IHW + pix;
        float a = ain[p + ain_off];
        dzin[p + dzin_off] = (a > 0.f) ? acc[g] : 0.f;
    }
}

// ---------------- r19: OC-split conv backward dX (deep layers) ----------------
template<int IC,int IH,int IW,int OC,int OH,int OW,int ICG,int BLK,int KOS>
__global__ __launch_bounds__(BLK) void conv_bwd_dx2k(
    const float* __restrict__ dzbuf, int dz_off,
    const float* __restrict__ fw, int woff,
    float* __restrict__ pbuf)
{
    constexpr int IHW = IH*IW, OHW = OH*OW, NICG = IC/ICG, PB = IHW/BLK;
    constexpr int OCC = OC/KOS;
    __shared__ float wlds[OCC*9*ICG];
    int bi = blockIdx.x;
    int pb  = bi % PB;
    int icg = (bi / PB) % NICG;
    int kos = (bi / (PB * NICG)) % KOS;
    int b   = bi / (PB * NICG * KOS);
    int ic0 = icg * ICG;
    int ocb = kos * OCC;
    const float* fwp = fw + (long)b * PT + woff;
    for (int i = threadIdx.x; i < OCC*9*ICG; i += BLK) {
        int g = i % ICG; int rem = i / ICG; int k = rem % 9; int ocl = rem / 9;
        wlds[i] = fwp[((long)(ocb + ocl) * IC + ic0 + g) * 9 + k];
    }
    __syncthreads();

    int pix = pb * BLK + threadIdx.x;
    int ih = pix / IW, iw = pix % IW;
    int kh0 = (ih + 1) & 1, kw0 = (iw + 1) & 1;
    int ohA = (ih + 1 - kh0) >> 1, owA = (iw + 1 - kw0) >> 1;
    float mhA = (ohA < OH) ? 1.f : 0.f;   float mhB = (kh0 == 0) ? 1.f : 0.f;
    float mwA = (owA < OW) ? 1.f : 0.f;   float mwB = (kw0 == 0) ? 1.f : 0.f;
    int ohB = ohA - 1, owB = owA - 1;
    int ohAc = (ohA < OH) ? ohA : 0;  int owAc = (owA < OW) ? owA : 0;
    int ohBc = (ohB >= 0) ? ohB : 0;  int owBc = (owB >= 0) ? owB : 0;

    int oAA = ohAc*OW + owAc; float mAA = mhA*mwA; int kAA = kh0*3 + kw0;
    int oAB = ohAc*OW + owBc; float mAB = mhA*mwB; int kAB = kh0*3 + kw0 + 2;
    int oBA = ohBc*OW + owAc; float mBA = mhB*mwA; int kBA = (kh0+2)*3 + kw0;
    int oBB = ohBc*OW + owBc; float mBB = mhB*mwB; int kBB = (kh0+2)*3 + kw0 + 2;

    const float* dzp = dzbuf + (long)b * ATOT + dz_off;
    float acc[ICG];
    #pragma unroll
    for (int g = 0; g < ICG; ++g) acc[g] = 0.f;

    for (int ocl = 0; ocl < OCC; ++ocl) {
        const float* dzo = dzp + (ocb + ocl) * OHW;
        float dAA = dzo[oAA] * mAA;
        float dAB = dzo[oAB] * mAB;
        float dBA = dzo[oBA] * mBA;
        float dBB = dzo[oBB] * mBB;
        const float* w = wlds + ocl * 9 * ICG;
        #pragma unroll
        for (int g = 0; g < ICG; ++g)
            acc[g] += dAA * w[kAA*ICG+g] + dAB * w[kAB*ICG+g]
                    + dBA * w[kBA*ICG+g] + dBB * w[kBB*ICG+g];
    }
    float* pp = pbuf + ((long)kos * NB + b) * ((long)IC * IHW);
    #pragma unroll
    for (int g = 0; g < ICG; ++g)
        pp[(long)(ic0 + g) * IHW + pix] = acc[g];
}

// r19: sum KOS dx partials + ReLU mask -> dzin
template<int KOS>
__global__ __launch_bounds__(256) void ksum_dx(
    const float* __restrict__ pbuf, const float* __restrict__ ain, int ain_off,
    float* __restrict__ dzin, int dzin_off, long ichw)
{
    long idx = (long)blockIdx.x * 256 + threadIdx.x;
    long total = (long)NB * ichw;
    if (idx >= total) return;
    int b = (int)(idx / ichw);
    long rem = idx % ichw;
    float s = 0.f;
    #pragma unroll
    for (int kos = 0; kos < KOS; ++kos)
        s += pbuf[((long)kos * NB + b) * ichw + rem];
    long p = (long)b * ATOT + rem;
    float a = ain[p + ain_off];
    dzin[p + dzin_off] = (a > 0.f) ? s : 0.f;
}

// ---------------- conv backward dW+db: one wave per (b, oc, ic) — kept for L1 ----------------
template<int IC,int IH,int IW,int OC,int OH,int OW,int S>
__global__ __launch_bounds__(64) void conv_bwd_dw2(
    float* __restrict__ fw, int woff, int boff,
    const float* __restrict__ dzbuf, int dz_off,
    const float* __restrict__ xb, long x_ts,
    const float* __restrict__ loglr)
{
    constexpr int OHW = OH*OW;
    int bi = blockIdx.x;
    int ic = bi % IC; int oc = (bi / IC) % OC; int b = bi / (IC * OC);
    int lane = threadIdx.x;
    const float* dzp = dzbuf + (long)b * ATOT + dz_off + (long)oc * OHW;
    const float* xp  = xb + (long)b * x_ts + (long)ic * IH * IW;

    float acc[10];
    #pragma unroll
    for (int k = 0; k < 10; ++k) acc[k] = 0.f;

    for (int pos = lane; pos < OHW; pos += 64) {
        float dzv = dzp[pos];
        int oh = pos / OW, ow = pos % OW;
        int ihb = oh * S - 1, iwb = ow * S - 1;
        acc[9] += dzv;
        #pragma unroll
        for (int kh = 0; kh < 3; ++kh) {
            int ih = ihb + kh;
            bool hv = ((unsigned)ih < (unsigned)IH);
            #pragma unroll
            for (int kw = 0; kw < 3; ++kw) {
                int iw = iwb + kw;
                float xv = (hv && (unsigned)iw < (unsigned)IW) ? xp[ih * IW + iw] : 0.f;
                acc[kh*3+kw] += dzv * xv;
            }
        }
    }
    #pragma unroll
    for (int k = 0; k < 10; ++k)
        for (int off = 32; off; off >>= 1) acc[k] += __shfl_down(acc[k], off, 64);

    if (lane == 0) {
        float lr = expf(loglr[0]);
        float* wp = fw + (long)b * PT + woff + ((long)oc * IC + ic) * 9;
        #pragma unroll
        for (int k = 0; k < 9; ++k) wp[k] -= lr * acc[k];
        if (ic == 0) fw[(long)b * PT + boff + oc] -= lr * acc[9];
    }
}

// ---------------- r16: spatially-split dW (L0) + finalize ----------------
template<int IC,int IH,int IW,int OC,int OH,int OW,int S,int NSP>
__global__ __launch_bounds__(64) void conv_bwd_dw2s(
    float* __restrict__ pbuf,
    const float* __restrict__ dzbuf, int dz_off,
    const float* __restrict__ xb, long x_ts)
{
    constexpr int OHW = OH*OW, CH = OHW/NSP;
    int bi = blockIdx.x;
    int sp = bi % NSP; int ic = (bi / NSP) % IC;
    int oc = (bi / (NSP*IC)) % OC; int b = bi / (NSP*IC*OC);
    int lane = threadIdx.x;
    const float* dzp = dzbuf + (long)b * ATOT + dz_off + (long)oc * OHW;
    const float* xp  = xb + (long)b * x_ts + (long)ic * IH * IW;

    float acc[10];
    #pragma unroll
    for (int k = 0; k < 10; ++k) acc[k] = 0.f;

    for (int pos = sp*CH + lane; pos < sp*CH + CH; pos += 64) {
        float dzv = dzp[pos];
        int oh = pos / OW, ow = pos % OW;
        int ihb = oh * S - 1, iwb = ow * S - 1;
        acc[9] += dzv;
        #pragma unroll
        for (int kh = 0; kh < 3; ++kh) {
            int ih = ihb + kh;
            bool hv = ((unsigned)ih < (unsigned)IH);
            #pragma unroll
            for (int kw = 0; kw < 3; ++kw) {
                int iw = iwb + kw;
                float xv = (hv && (unsigned)iw < (unsigned)IW) ? xp[ih * IW + iw] : 0.f;
                acc[kh*3+kw] += dzv * xv;
            }
        }
    }
    #pragma unroll
    for (int k = 0; k < 10; ++k)
        for (int off = 32; off; off >>= 1) acc[k] += __shfl_down(acc[k], off, 64);

    if (lane == 0) {
        float* pp = pbuf + ((((long)sp*NB + b)*OC + oc)*IC + ic)*10;
        #pragma unroll
        for (int k = 0; k < 10; ++k) pp[k] = acc[k];
    }
}

template<int NSP>
__global__ void dw_finalize(const float* __restrict__ pbuf, float* __restrict__ fw,
                            int woff, int boff, const float* __restrict__ loglr,
                            int OC, int IC)
{
    int idx = blockIdx.x * blockDim.x + threadIdx.x;
    int total = NB * OC * IC * 10;
    if (idx >= total) return;
    int k = idx % 10; int r = idx / 10;
    int ic = r % IC; r /= IC;
    int oc = r % OC; int b = r / OC;
    float s = 0.f;
    #pragma unroll
    for (int sp = 0; sp < NSP; ++sp)
        s += pbuf[((((long)sp*NB + b)*OC + oc)*IC + ic)*10 + k];
    float lr = expf(loglr[0]);
    if (k < 9)
        fw[(long)b*PT + woff + ((long)oc*IC + ic)*9 + k] -= lr * s;
    else if (ic == 0)
        fw[(long)b*PT + boff + oc] -= lr * s;
}

// ---------------- final loss / eval ----------------
__global__ void final_loss_eval(const float* __restrict__ logit_base,
                                const int* __restrict__ test_y,
                                float* __restrict__ out, int l0, int Lc)
{
    int idx = blockIdx.x * blockDim.x + threadIdx.x;
    if (idx >= NB * Lc) return;
    int n = idx % Lc, b = idx / Lc;
    int l = l0 + n;
    const float* lo = logit_base + ((long)b * NL + l) * NCLS;
    float mx = -1e30f; int am = 0;
    for (int c = 0; c < NCLS; ++c) { float v = lo[c]; if (v > mx) { mx = v; am = c; } }
    float se = 0.f;
    for (int c = 0; c < NCLS; ++c) se += expf(lo[c] - mx);
    int y = test_y[b * NL + l];
    out[b * NL + l] = -(lo[y] - mx - logf(se));
    out[129 + b * NL + l] = (am == y) ? 1.f : 0.f;
}

__global__ void write_lr(const float* __restrict__ loglr, float* __restrict__ out)
{
    if (threadIdx.x == 0 && blockIdx.x == 0) out[128] = expf(loglr[0]);
}

// ---------------- host orchestration ----------------
extern "C" void kernel_launch(void* const* d_in, const int* in_sizes, int n_in,
                              void* d_out, int out_size, void* d_ws, size_t ws_size,
                              hipStream_t stream)
{
    const float* loglr      = (const float*)d_in[12];
    const float* train_x    = (const float*)d_in[13];
    const float* test_x     = (const float*)d_in[14];
    const float* train_gate = (const float*)d_in[15];
    const float* test_gate  = (const float*)d_in[16];
    const int*   train_y    = (const int*)d_in[17];
    const int*   test_y     = (const int*)d_in[18];
    float* out = (float*)d_out;

    const long base = (long)NB*PT + 2L*NB*ATOT + 2L*NB*NCLS;
    int LCr = 4;
    if (ws_size >= (size_t)(base + 16L*1572864) * 4) LCr = 16;
    else if (ws_size >= (size_t)(base + 8L*1572864) * 4) LCr = 8;

    float* ws   = (float*)d_ws;
    float* FWp  = ws;
    float* AINp = FWp  + (long)NB * PT;
    float* DZp  = AINp + (long)NB * ATOT;
    float* LOGIp= DZp  + (long)NB * ATOT;
    float* DLOGp= LOGIp + NB * NCLS;
    float* TAp  = DLOGp + NB * NCLS;
    float* TBp  = TAp + (long)NB * LCr * 131072;

    // train-phase scratch (TAp is free until the test phase; min TAp = 4.19M floats at LCr=4)
    float* P3t = TAp;                       // 2*NB*256*64  = 262144
    float* P4t = TAp + 262144;              // 4*NB*256*16  = 131072
    float* PW0 = TAp + 262144 + 131072;     // 8*NB*32*3*10 =  61440
    float* PDX = TAp + 458752;              // dx partials, max 4*NB*32768 = 1,048,576 -> ends 1.51M

    Params12 ps;
    for (int j = 0; j < 12; ++j) ps.p[j] = (const float*)d_in[j];
    {
        long tot = (long)NB * PT;
        bcast_kernel<<<(int)((tot + 255) / 256), 256, 0, stream>>>(ps, FWp);
    }

    for (int t = 0; t < NT; ++t) {
        // ---- forward convs (train) ----
        conv_fwd_u<3,64,64,32,64,64,1,3,256><<<4096, 256, 0, stream>>>(
            train_x + (long)t * CHW, (long)NT * CHW, FWp, OFF_W0, OFF_B0, AINp + A1, (long)ATOT);
        conv_fwd_u<32,64,64,64,32,32,2,4,256><<<2048, 256, 0, stream>>>(
            AINp + A1, (long)ATOT, FWp, OFF_W1, OFF_B1, AINp + A2, (long)ATOT);
        conv_fwd_u<64,32,32,128,16,16,2,4,256><<<1024, 256, 0, stream>>>(
            AINp + A2, (long)ATOT, FWp, OFF_W2, OFF_B2, AINp + A3, (long)ATOT);
        // L3: KS=2, oc-uniform scalar weights -> 4096 waves (r22: XCD-swizzled)
        conv_fwd_us<128,16,16,256,8,8,2,4, 2><<<NB*2*256, 64, 0, stream>>>(
            AINp + A3, (long)ATOT, FWp, OFF_W3, P3t);
        ksum_relu<2><<<(NB*256*64 + 255) / 256, 256, 0, stream>>>(
            P3t, FWp, OFF_B3, AINp + A4, (long)ATOT, 1, 256, 64);
        // L4: KS=4 -> 2048 waves (r22: XCD-swizzled)
        conv_fwd_uks<256,8,8,256,4,4,2,8,64, 4><<<2048, 64, 0, stream>>>(
            AINp + A4, (long)ATOT, FWp, OFF_W4, P4t);
        ksum_relu<4><<<(NB*256*16 + 255) / 256, 256, 0, stream>>>(
            P4t, FWp, OFF_B4, AINp + A5, (long)ATOT, 1, 256, 16);

        {
            long waves = (long)NB * NCLS;
            head_fwd<<<(int)((waves * 64 + 255) / 256), 256, 0, stream>>>(
                AINp + A5, (long)ATOT, 0,
                train_gate + (long)t * FEAT, (long)NT * FEAT, 0,
                FWp, LOGIp, (long)NCLS, 0, 1);
        }
        softmax_dlogit<<<NB, 128, 0, stream>>>(LOGIp, train_y, t, DLOGp);
        head_bwd_dz5<<<(NB * FEAT + 255) / 256, 256, 0, stream>>>(
            FWp, DLOGp, AINp, train_gate + (long)t * FEAT, (long)NT * FEAT, DZp);
        {
            long tot = (long)NB * NCLS * FEAT;
            head_update<<<(int)((tot + 255) / 256), 256, 0, stream>>>(
                FWp, DLOGp, AINp, train_gate + (long)t * FEAT, (long)NT * FEAT, loglr);
        }

        // ---- backward chain (r19 structure, FROZEN) ----
        conv_bwd_dx2k<256,8,8,256,4,4,2,64, 4><<<4096, 64, 0, stream>>>(
            DZp, A5, FWp, OFF_W4, PDX);
        ksum_dx<4><<<(int)(((long)NB*16384 + 255) / 256), 256, 0, stream>>>(
            PDX, AINp, A4, DZp, A4, 16384);
        conv_bwd_dwg<256,8,8,256,4,4,2, 64,8,2, 4><<<1024, 256, 0, stream>>>(
            FWp, OFF_W4, OFF_B4, DZp, A5, AINp + A4, (long)ATOT, loglr);

        conv_bwd_dx2k<128,16,16,256,8,8,4,256, 4><<<1024, 256, 0, stream>>>(
            DZp, A4, FWp, OFF_W3, PDX);
        ksum_dx<4><<<(int)(((long)NB*32768 + 255) / 256), 256, 0, stream>>>(
            PDX, AINp, A3, DZp, A3, 32768);
        conv_bwd_dwg<128,16,16,256,8,8,2, 64,8,2, 8><<<512, 256, 0, stream>>>(
            FWp, OFF_W3, OFF_B3, DZp, A4, AINp + A3, (long)ATOT, loglr);

        conv_bwd_dx2k<64,32,32,128,16,16,4,256, 2><<<1024, 256, 0, stream>>>(
            DZp, A3, FWp, OFF_W2, PDX);
        ksum_dx<2><<<(int)(((long)NB*65536 + 255) / 256), 256, 0, stream>>>(
            PDX, AINp, A2, DZp, A2, 65536);
        conv_bwd_dwg<64,32,32,128,16,16,2, 32,8,1, 4><<<256, 256, 0, stream>>>(
            FWp, OFF_W2, OFF_B2, DZp, A3, AINp + A2, (long)ATOT, loglr);

        conv_bwd_dx2<32,64,64,64,32,32,4,256><<<8*8*16, 256, 0, stream>>>(
            DZp, A2, FWp, OFF_W1, AINp, A1, DZp, A1);
        conv_bwd_dw2<32,64,64,64,32,32,2><<<8*64*32, 64, 0, stream>>>(
            FWp, OFF_W1, OFF_B1, DZp, A2, AINp + A1, (long)ATOT, loglr);
        conv_bwd_dw2s<3,64,64,32,64,64,1, 8><<<8*32*3*8, 64, 0, stream>>>(
            PW0, DZp, A1, train_x + (long)t * CHW, (long)NT * CHW);
        dw_finalize<8><<<(NB*32*3*10 + 255) / 256, 256, 0, stream>>>(
            PW0, FWp, OFF_W0, OFF_B0, loglr, 32, 3);
    }

    // 3) test forward
    if (LCr == 16) {
        conv_fwd2<3,64,64,32,64,64,1, 32,1,3><<<NB*16*16, 256, 0, stream>>>(
            test_x, (long)NL * CHW, CHW,
            FWp, OFF_W0, OFF_B0, TAp, 16L * 131072, 16);

        // r23: gx with XCD swizzle + phase-split LDS (bank-conflict-free)
        // L1 (32->64): TOCP=16, grid = 2048
        conv_fwd_gx<32,64,64, 64,32,32, 2, 1,2,8, 1, 16, 16><<<2048, 256, 0, stream>>>(
            TAp, 16L*131072, 131072, FWp, OFF_W1, OFF_B1, TBp, 16L*65536, nullptr);
        // L2 (64->128): TOCP=8 -> NOCG=4, grid = 2048
        conv_fwd_gx<64,32,32, 128,16,16, 2, 1,4,8, 1, 16, 8><<<2048, 256, 0, stream>>>(
            TBp, 16L*65536, 65536, FWp, OFF_W2, OFF_B2, TAp, 16L*32768, nullptr);
        // L3 (128->256): KS=4 partials, TOCP=16, grid = 2048
        {
            float* P3 = TAp + 4194304;   // 4 * 8*16*256*64 = 8,388,608 -> ends 12.58M < 16.78M
            conv_fwd_gx<128,16,16, 256,8,8, 2, 1,8,8, 4, 16, 16><<<2048, 256, 0, stream>>>(
                TAp, 16L*32768, 32768, FWp, OFF_W3, 0, nullptr, 0, P3);
            ksum_relu<4><<<(int)(((long)NB*16*256*64 + 255) / 256), 256, 0, stream>>>(
                P3, FWp, OFF_B3, TBp, 16L * 16384, 16, 256, 64);
        }
        // L4 (256->256): TOCP=8 -> NOCG=8, KS=8, grid = 2048
        {
            float* P4 = TBp + 2097152;   // 8 * 8*16*256*16 = 4,194,304 -> ends 6.29M < 8.39M
            conv_fwd_gx<256,8,8, 256,4,4, 2, 4,4,8, 8, 16, 8><<<2048, 256, 0, stream>>>(
                TBp, 16L*16384, 16384, FWp, OFF_W4, 0, nullptr, 0, P4);
            ksum_relu<8><<<(int)(((long)NB*16*256*16 + 255) / 256), 256, 0, stream>>>(
                P4, FWp, OFF_B4, TAp, 16L * 4096, 16, 256, 16);
        }
        {
            long waves = (long)NB * 16 * NCLS;
            head_fwd<<<(int)((waves * 64 + 255) / 256), 256, 0, stream>>>(
                TAp, 16L * FEAT, FEAT,
                test_gate, (long)NL * FEAT, FEAT,
                FWp, out + 257, (long)NL * NCLS, NCLS, 16);
        }
    } else {
        for (int c = 0; c < NL / LCr; ++c) {
            int l0 = c * LCr;
            conv_fwd2<3,64,64,32,64,64,1, 32,1,3><<<NB*LCr*16, 256, 0, stream>>>(
                test_x + (long)l0 * CHW, (long)NL * CHW, CHW,
                FWp, OFF_W0, OFF_B0, TAp, (long)LCr * 131072, LCr);
            conv_fwd2<32,64,64,64,32,32,2, 16,1,8><<<NB*LCr*16, 256, 0, stream>>>(
                TAp, (long)LCr * 131072, 131072,
                FWp, OFF_W1, OFF_B1, TBp, (long)LCr * 65536, LCr);
            conv_fwd2<64,32,32,128,16,16,2, 16,1,8><<<NB*LCr*8, 256, 0, stream>>>(
                TBp, (long)LCr * 65536, 65536,
                FWp, OFF_W2, OFF_B2, TAp, (long)LCr * 32768, LCr);
            conv_fwd2<128,16,16,256,8,8,2, 8,4,8><<<NB*LCr*8, 256, 0, stream>>>(
                TAp, (long)LCr * 32768, 32768,
                FWp, OFF_W3, OFF_B3, TBp, (long)LCr * 16384, LCr);
            conv_fwd2<256,8,8,256,4,4,2, 4,16,8><<<NB*LCr*4, 256, 0, stream>>>(
                TBp, (long)LCr * 16384, 16384,
                FWp, OFF_W4, OFF_B4, TAp, (long)LCr * 4096, LCr);
            {
                long waves = (long)NB * LCr * NCLS;
                head_fwd<<<(int)((waves * 64 + 255) / 256), 256, 0, stream>>>(
                    TAp, (long)LCr * FEAT, FEAT,
                    test_gate + (long)l0 * FEAT, (long)NL * FEAT, FEAT,
                    FWp, out + 257 + (long)l0 * NCLS, (long)NL * NCLS, NCLS, LCr);
            }
        }
    }
    final_loss_eval<<<(NB * NL + 255) / 256, 256, 0, stream>>>(
        out + 257, test_y, out, 0, NL);
    write_lr<<<1, 1, 0, stream>>>(loglr, out);
}

// Round 11
// 3818.617 us; speedup vs baseline: 1.0142x; 1.0142x over previous
//
#include <hip/hip_runtime.h>

// ---------------- problem constants ----------------
#define NB 8          // meta-batch (tasks)
#define NT 5          // inner steps
#define NL 16         // test examples per task
#define NCLS 100
#define FEAT 4096
#define CHW (3*64*64) // 12288

// per-task fast-weight block offsets (floats)
#define OFF_W0 0
#define OFF_B0 864
#define OFF_W1 896
#define OFF_B1 19328
#define OFF_W2 19392
#define OFF_B2 93120
#define OFF_W3 93248
#define OFF_B3 388160
#define OFF_W4 388416
#define OFF_B4 978240
#define OFF_WO 978496
#define OFF_BO 1388096
#define PT     1388196   // floats per task

// per-task inner activation block offsets (floats)
#define A1 0          // 32*64*64 = 131072
#define A2 131072     // 64*32*32 =  65536
#define A3 196608     // 128*16*16 = 32768
#define A4 229376     // 256*8*8  =  16384
#define A5 245760     // 256*4*4  =   4096
#define ATOT 249856

struct Params12 { const float* p[12]; };

// r22: bijective XCD swizzle (T1/m204) — kept ONLY on test-path gx (verified win:
// FETCH 52->17.6MB, 170->138us). r24: REVERTED on train us/uks (suspected aggregate
// regression: per-task XCD pinning cuts effective BW parallelism on short dispatches).
__device__ __forceinline__ int xcd_swz(int b, int cpx) {
    return (b & 7) * cpx + (b >> 3);
}

// ---------------- broadcast initial params to per-task fast weights ----------------
__global__ void bcast_kernel(Params12 ps, float* __restrict__ fw) {
    const int offs[13] = {OFF_W0,OFF_B0,OFF_W1,OFF_B1,OFF_W2,OFF_B2,OFF_W3,OFF_B3,
                          OFF_W4,OFF_B4,OFF_WO,OFF_BO,PT};
    long idx = (long)blockIdx.x * blockDim.x + threadIdx.x;
    long total = (long)NB * PT;
    if (idx >= total) return;
    int i = (int)(idx % PT);
    int j = 11;
    while (j > 0 && i < offs[j]) --j;
    fw[idx] = ps.p[j][i - offs[j]];
}

// ---------------- train-path conv: conv_fwd mapping + UF-blocked loads (proven r7) ----------------
template<int IC,int IH,int IW,int OC,int OH,int OW,int S,int UF,int BS>
__global__ __launch_bounds__(BS) void conv_fwd_u(
    const float* __restrict__ xb, long x_ts,
    const float* __restrict__ fw, int woff, int boff,
    float* __restrict__ yb, long y_ts)
{
    constexpr int OHW = OH*OW, IHW = IH*IW;
    long idx = (long)blockIdx.x * BS + threadIdx.x;
    int pix = (int)(idx % OHW); long r = idx / OHW;
    int oc = (int)(r % OC); int b = (int)(r / OC);
    int oh = pix / OW, ow = pix % OW;
    int ih0 = oh*S - 1, iw0 = ow*S - 1;

    const float* x = xb + (long)b * x_ts;
    const float* w = fw + (long)b * PT + woff + (long)oc * IC * 9;
    float acc = fw[(long)b * PT + boff + oc];

    #pragma unroll 1
    for (int ic0 = 0; ic0 < IC; ic0 += UF) {
        float xv[UF][9];
        #pragma unroll
        for (int u = 0; u < UF; ++u) {
            const float* xc = x + (long)(ic0 + u) * IHW;
            #pragma unroll
            for (int kh = 0; kh < 3; ++kh) {
                int ih = ih0 + kh;
                #pragma unroll
                for (int kw = 0; kw < 3; ++kw) {
                    int iw = iw0 + kw;
                    bool v = ((unsigned)ih < (unsigned)IH) && ((unsigned)iw < (unsigned)IW);
                    xv[u][kh*3+kw] = v ? xc[ih*IW + iw] : 0.f;
                }
            }
        }
        #pragma unroll
        for (int u = 0; u < UF; ++u) {
            const float* wc = w + (ic0 + u) * 9;
            #pragma unroll
            for (int k = 0; k < 9; ++k)
                acc += xv[u][k] * wc[k];
        }
    }
    yb[(long)b * y_ts + (long)oc * OHW + pix] = fmaxf(acc, 0.f);
}

// ---------------- r16/r24: IC-split train conv (L4) — swizzle REVERTED (r21 form) ----------------
template<int IC,int IH,int IW,int OC,int OH,int OW,int S,int UF,int BS,int KS>
__global__ __launch_bounds__(BS) void conv_fwd_uks(
    const float* __restrict__ xb, long x_ts,
    const float* __restrict__ fw, int woff,
    float* __restrict__ pb)
{
    constexpr int OHW = OH*OW, IHW = IH*IW;
    constexpr int ICC = IC/KS;
    long idx = (long)blockIdx.x * BS + threadIdx.x;
    int pix = (int)(idx % OHW); long r = idx / OHW;
    int oc = (int)(r % OC); r /= OC;
    int ks = (int)(r % KS); int b = (int)(r / KS);
    int oh = pix / OW, ow = pix % OW;
    int ih0 = oh*S - 1, iw0 = ow*S - 1;

    const float* x = xb + (long)b * x_ts;
    const float* w = fw + (long)b * PT + woff + (long)oc * IC * 9;
    float acc = 0.f;

    #pragma unroll 1
    for (int ic0 = ks*ICC; ic0 < (ks+1)*ICC; ic0 += UF) {
        float xv[UF][9];
        #pragma unroll
        for (int u = 0; u < UF; ++u) {
            const float* xc = x + (long)(ic0 + u) * IHW;
            #pragma unroll
            for (int kh = 0; kh < 3; ++kh) {
                int ih = ih0 + kh;
                #pragma unroll
                for (int kw = 0; kw < 3; ++kw) {
                    int iw = iw0 + kw;
                    bool v = ((unsigned)ih < (unsigned)IH) && ((unsigned)iw < (unsigned)IW);
                    xv[u][kh*3+kw] = v ? xc[ih*IW + iw] : 0.f;
                }
            }
        }
        #pragma unroll
        for (int u = 0; u < UF; ++u) {
            const float* wc = w + (ic0 + u) * 9;
            #pragma unroll
            for (int k = 0; k < 9; ++k)
                acc += xv[u][k] * wc[k];
        }
    }
    pb[((long)ks*NB + b) * ((long)OC*OHW) + (long)oc*OHW + pix] = acc;
}

// ---------------- r17/r24: oc-uniform scalar-weight train conv (L3) — swizzle REVERTED ----------------
template<int IC,int IH,int IW,int OC,int OH,int OW,int S,int UF,int KS>
__global__ __launch_bounds__(64) void conv_fwd_us(
    const float* __restrict__ xb, long x_ts,
    const float* __restrict__ fw, int woff,
    float* __restrict__ pb)
{
    constexpr int OHW = OH*OW, IHW = IH*IW, ICC = IC/KS;
    static_assert(OHW == 64, "one wave = one oc-plane");
    int bi = blockIdx.x;
    int oc = bi % OC; int ks = (bi / OC) % KS; int b = bi / (OC*KS);
    int pix = threadIdx.x;
    int oh = pix / OW, ow = pix % OW;
    int ih0 = oh*S - 1, iw0 = ow*S - 1;

    const float* x = xb + (long)b * x_ts;
    const float* w = fw + (long)b * PT + woff + (long)oc * IC * 9;  // uniform

    float acc = 0.f;
    #pragma unroll 1
    for (int ic0 = ks*ICC; ic0 < (ks+1)*ICC; ic0 += UF) {
        float xv[UF][9];
        #pragma unroll
        for (int u = 0; u < UF; ++u) {
            const float* xc = x + (long)(ic0 + u) * IHW;
            #pragma unroll
            for (int kh = 0; kh < 3; ++kh) {
                int ih = ih0 + kh;
                #pragma unroll
                for (int kw = 0; kw < 3; ++kw) {
                    int iw = iw0 + kw;
                    bool v = ((unsigned)ih < (unsigned)IH) && ((unsigned)iw < (unsigned)IW);
                    xv[u][kh*3+kw] = v ? xc[ih*IW + iw] : 0.f;
                }
            }
        }
        #pragma unroll
        for (int u = 0; u < UF; ++u) {
            const float* wc = w + (ic0 + u) * 9;
            #pragma unroll
            for (int k = 0; k < 9; ++k)
                acc += xv[u][k] * wc[k];
        }
    }
    pb[((long)ks*NB + b) * ((long)OC*OHW) + (long)oc*OHW + pix] = acc;
}

// ---------------- tiled conv fwd (test path L0 + fallback path) — proven r5 ----------------
template<int IC,int IH,int IW,int OC,int OH,int OW,int S,int TOC,int NSUB,int ICB>
__global__ __launch_bounds__(256) void conv_fwd2(
    const float* __restrict__ xb, long x_ts, long x_es,
    const float* __restrict__ fw, int woff, int boff,
    float* __restrict__ yb, long y_ts, int N)
{
    constexpr int OHW = OH*OW, IHW = IH*IW;
    constexpr int PPB = 256/NSUB;
    constexpr int TILES = OHW/PPB;
    constexpr int OCB = NSUB*TOC;
    constexpr int NOCG = OC/OCB;
    __shared__ float wlds[ICB*9*OCB];

    int bi = blockIdx.x;
    int tile = bi % TILES;
    int ocg  = (bi / TILES) % NOCG;
    int n    = (bi / (TILES*NOCG)) % N;
    int b    = bi / (TILES*NOCG*N);

    int tid = threadIdx.x;
    int pixl = tid % PPB, sub = tid / PPB;
    int pix = tile * PPB + pixl;
    int oc0 = ocg * OCB + sub * TOC;
    int oh = pix / OW, ow = pix % OW;
    int ih0 = oh*S - 1, iw0 = ow*S - 1;

    const float* xp  = xb + (long)b * x_ts + (long)n * x_es;
    const float* fwp = fw + (long)b * PT + woff;
    const float* bp  = fw + (long)b * PT + boff;

    float acc[TOC];
    #pragma unroll
    for (int t = 0; t < TOC; ++t) acc[t] = bp[oc0 + t];

    #pragma unroll 1
    for (int ic0i = 0; ic0i < IC; ic0i += ICB) {
        __syncthreads();
        for (int i = tid; i < ICB*9*OCB; i += 256) {
            int o = i % OCB; int rem = i / OCB; int k = rem % 9; int icb = rem / 9;
            wlds[i] = fwp[((long)(ocg*OCB + o) * IC + ic0i + icb) * 9 + k];
        }
        __syncthreads();
        #pragma unroll 2
        for (int icb = 0; icb < ICB; ++icb) {
            const float* xc = xp + (long)(ic0i + icb) * IHW;
            float xv[9];
            #pragma unroll
            for (int kh = 0; kh < 3; ++kh)
            #pragma unroll
            for (int kw = 0; kw < 3; ++kw) {
                int ih = ih0 + kh, iw = iw0 + kw;
                bool v = ((unsigned)ih < (unsigned)IH) && ((unsigned)iw < (unsigned)IW);
                xv[kh*3+kw] = v ? xc[ih*IW + iw] : 0.f;
            }
            const float* wl = wlds + icb*9*OCB + sub*TOC;
            #pragma unroll
            for (int k = 0; k < 9; ++k) {
                #pragma unroll
                for (int t = 0; t < TOC; ++t)
                    acc[t] += xv[k] * wl[k*OCB + t];
            }
        }
    }

    float* yp = yb + (long)b * y_ts;
    #pragma unroll
    for (int t = 0; t < TOC; ++t)
        yp[((long)n*OC + oc0 + t) * OHW + pix] = fmaxf(acc[t], 0.f);
}

// ---------------- r23: gx with XCD swizzle + phase-split LDS (test path, FROZEN) ----------------
template<int IC,int IH,int IW,int OC,int OH,int OW,int S,
         int NG,int TH,int ICB,int KS,int NTOT,int TOCP>
__global__ __launch_bounds__(256, 8) void conv_fwd_gx(
    const float* __restrict__ xb, long x_ts, long x_es,
    const float* __restrict__ fw, int woff, int boff,
    float* __restrict__ yb, long y_ts,          // used when KS==1
    float* __restrict__ pb)                     // used when KS>1
{
    constexpr int OHW = OH*OW, IHW = IH*IW;
    constexpr int OCB2 = 4*TOCP;
    constexpr int NOCG = OC/OCB2;
    constexpr int RT = OH/TH;
    constexpr int NGRP = NTOT/NG;
    constexpr int ICC = IC/KS;
    constexpr int PW = IW + 1;                  // left zero-border only (S==2)
    constexpr int HALF = (PW + 1)/2;            // even-phase slot count
    constexpr int TGT = (OW >= 32) ? (PW % 16) : ((OW/2) % 16);
    constexpr int RS = PW + ((TGT - (PW % 16) + 16) % 16);   // bank-tiling row stride
    constexpr int PROWS = (TH-1)*S + 3;         // rows incl. top border + halo
    constexpr int XP = (PROWS*RS) | 1;          // odd plane stride
    constexpr int GRID = NOCG*RT*NGRP*KS*NB;
    static_assert(GRID % 8 == 0, "xcd swizzle needs grid%8==0");
    static_assert(NG*TH*OW == 64, "lanes must cover exactly 64 pixels");
    static_assert(S == 2, "padding derivation assumes stride 2");
    static_assert(ICC % ICB == 0, "chunking");

    __shared__ float xs[NG*ICB*XP];

    int bi = xcd_swz(blockIdx.x, GRID >> 3);
    int ocg = bi % NOCG;
    int rt  = (bi / NOCG) % RT;
    int ng  = (bi / (NOCG*RT)) % NGRP;
    int ks  = (bi / (NOCG*RT*NGRP)) % KS;
    int b   = bi / (NOCG*RT*NGRP*KS);

    int tid = threadIdx.x;
    int pl = tid & 63;
    int ocsub = __builtin_amdgcn_readfirstlane(tid >> 6);   // wave-uniform -> SGPR
    int nl = pl / (TH*OW);
    int prow = (pl / OW) % TH;
    int pcol = pl % OW;
    int oc0 = ocg*OCB2 + ocsub*TOCP;                         // uniform

    const float* xbb = xb + (long)b * x_ts + (long)(ng*NG) * x_es;
    const float* wb  = fw + (long)b * PT + woff;             // uniform base

    float acc[TOCP];
    #pragma unroll
    for (int t = 0; t < TOCP; ++t)
        acc[t] = (KS == 1) ? fw[(long)b*PT + boff + oc0 + t] : 0.f;

    const int ih0t = rt*TH*S - 1;

    #pragma unroll 1
    for (int c = 0; c < ICC/ICB; ++c) {
        int ic0 = ks*ICC + c*ICB;
        if (c) __syncthreads();
        // stage padded x tile (phase-split columns, coalesced global row reads)
        for (int i = tid; i < NG*ICB*PROWS*PW; i += 256) {
            int cc = i % PW;
            int r  = (i / PW) % PROWS;
            int icb = (i / (PW*PROWS)) % ICB;
            int nl2 = i / (PW*PROWS*ICB);
            int ih = ih0t + r, iw = cc - 1;
            float v = 0.f;
            if (ih >= 0 && iw >= 0)
                v = xbb[(long)nl2 * x_es + (long)(ic0+icb)*IHW + ih*IW + iw];
            int cp = (cc & 1) ? (HALF + (cc >> 1)) : (cc >> 1);
            xs[(nl2*ICB + icb)*XP + r*RS + cp] = v;
        }
        __syncthreads();
        #pragma unroll 2
        for (int icb = 0; icb < ICB; ++icb) {
            int ic = ic0 + icb;
            const float* xr = xs + (nl*ICB + icb)*XP + (prow*S)*RS;
            float xv[9];
            #pragma unroll
            for (int kh = 0; kh < 3; ++kh) {
                xv[kh*3+0] = xr[kh*RS + pcol];          // c=2*pcol   (even phase)
                xv[kh*3+1] = xr[kh*RS + HALF + pcol];   // c=2*pcol+1 (odd phase)
                xv[kh*3+2] = xr[kh*RS + pcol + 1];      // c=2*pcol+2 (even phase)
            }
            const float* wr = wb + ((long)oc0*IC + ic)*9;     // uniform
            #pragma unroll
            for (int t = 0; t < TOCP; ++t) {
                const float* wt = wr + (long)t*IC*9;          // uniform
                #pragma unroll
                for (int k = 0; k < 9; ++k)
                    acc[t] += xv[k] * wt[k];
            }
        }
    }

    int n = ng*NG + nl;
    int pix = (rt*TH + prow)*OW + pcol;
    if (KS == 1) {
        float* yp = yb + (long)b * y_ts;
        #pragma unroll
        for (int t = 0; t < TOCP; ++t)
            yp[((long)n*OC + oc0 + t)*OHW + pix] = fmaxf(acc[t], 0.f);
    } else {
        float* yp = pb + ((long)ks*NB + b) * ((long)NTOT*OC*OHW);
        #pragma unroll
        for (int t = 0; t < TOCP; ++t)
            yp[((long)n*OC + oc0 + t)*OHW + pix] = acc[t];
    }
}

// ---------------- r14: deterministic KS-partial reduce + bias + relu ----------------
template<int KS>
__global__ __launch_bounds__(256) void ksum_relu(
    const float* __restrict__ pb, const float* __restrict__ fw, int boff,
    float* __restrict__ yb, long y_ts, int N, int OC, int OHW)
{
    long plane = (long)N * OC * OHW;
    long idx = (long)blockIdx.x * 256 + threadIdx.x;
    long total = (long)NB * plane;
    if (idx >= total) return;
    int b = (int)(idx / plane);
    long rem = idx % plane;
    int oc = (int)((rem / OHW) % OC);
    float s = fw[(long)b * PT + boff + oc];
    #pragma unroll
    for (int ks = 0; ks < KS; ++ks)
        s += pb[((long)ks * NB + b) * plane + rem];
    yb[(long)b * y_ts + rem] = fmaxf(s, 0.f);
}

// ---------------- r15: GEMM-tiled conv dW+db (train path, deep layers) ----------------
template<int IC,int IH,int IW,int OC,int OH,int OW,int S,int OCT,int ICT,int OCPT,int OHC>
__global__ __launch_bounds__(256) void conv_bwd_dwg(
    float* __restrict__ fw, int woff, int boff,
    const float* __restrict__ dzbuf, int dz_off,
    const float* __restrict__ xb, long x_ts,
    const float* __restrict__ loglr)
{
    constexpr int OHW = OH*OW, IHW = IH*IW;
    constexpr int IW2 = IW + 2;
    constexpr int RW  = OHC*S + 1;
    constexpr int XPRAW = RW * IW2;
    constexpr int XP = XPRAW | 1;
    constexpr int OHWC = OHC*OW;
    constexpr int DZP = OHWC + 1;
    constexpr int NCH = OH/OHC;
    constexpr int OCSL = OCT/OCPT;
    static_assert(OCSL*ICT == 256, "block must be 256 threads");
    static_assert((OW & (OW-1)) == 0, "OW power of two");
    constexpr int LOG_OW = (OW==4) ? 2 : ((OW==8) ? 3 : 4);
    constexpr int NOCG = OC/OCT, NICG = IC/ICT;

    __shared__ float dzs[OCT*DZP];
    __shared__ float xs[ICT*XP];

    int bi = blockIdx.x;
    int icg = bi % NICG;
    int ocg = (bi / NICG) % NOCG;
    int b   = bi / (NICG*NOCG);
    int oc0 = ocg*OCT, ic0 = icg*ICT;

    int tid = threadIdx.x;
    int ic_sub = tid % ICT;
    int oc_sub = tid / ICT;

    const float* dzp = dzbuf + (long)b*ATOT + dz_off + (long)oc0*OHW;
    const float* xp  = xb + (long)b*x_ts + (long)ic0*IHW;

    float acc[OCPT][9];
    float accb[OCPT];
    #pragma unroll
    for (int p = 0; p < OCPT; ++p) {
        accb[p] = 0.f;
        #pragma unroll
        for (int k = 0; k < 9; ++k) acc[p][k] = 0.f;
    }

    for (int c = 0; c < NCH; ++c) {
        if (c) __syncthreads();
        for (int i = tid; i < OCT*OHWC; i += 256) {
            int oc = i / OHWC, j = i % OHWC;
            dzs[oc*DZP + j] = dzp[(long)oc*OHW + c*OHWC + j];
        }
        for (int i = tid; i < ICT*XPRAW; i += 256) {
            int ic = i / XPRAW, j = i % XPRAW;
            int r = j / IW2, col = j % IW2;
            int ih = c*(OHC*S) - 1 + r;
            int iw = col - 1;
            float v = 0.f;
            if ((unsigned)ih < (unsigned)IH && (unsigned)iw < (unsigned)IW)
                v = xp[(long)ic*IHW + ih*IW + iw];
            xs[ic*XP + j] = v;
        }
        __syncthreads();

        const float* dzr = dzs + oc_sub*DZP;
        const float* xr0 = xs + ic_sub*XP;
        #pragma unroll 2
        for (int pos = 0; pos < OHWC; ++pos) {
            int ohl = pos >> LOG_OW;
            int ow  = pos & (OW-1);
            const float* xr = xr0 + (ohl*S)*IW2 + ow*S;
            float xv[9];
            #pragma unroll
            for (int kh = 0; kh < 3; ++kh)
                #pragma unroll
                for (int kw = 0; kw < 3; ++kw)
                    xv[kh*3+kw] = xr[kh*IW2 + kw];
            #pragma unroll
            for (int p = 0; p < OCPT; ++p) {
                float dzv = dzr[p*OCSL*DZP + pos];
                accb[p] += dzv;
                #pragma unroll
                for (int k = 0; k < 9; ++k) acc[p][k] += dzv * xv[k];
            }
        }
    }

    float lr = expf(loglr[0]);
    #pragma unroll
    for (int p = 0; p < OCPT; ++p) {
        int oc = oc0 + p*OCSL + oc_sub;
        float* wp = fw + (long)b*PT + woff + ((long)oc*IC + ic0 + ic_sub)*9;
        #pragma unroll
        for (int k = 0; k < 9; ++k) wp[k] -= lr * acc[p][k];
        if (ic_sub == 0 && icg == 0)
            fw[(long)b*PT + boff + oc] -= lr * accb[p];
    }
}

// ---------------- head forward ----------------
__global__ void head_fwd(const float* __restrict__ a5b, long a_ts, long a_es,
                         const float* __restrict__ gb, long g_ts, long g_es,
                         const float* __restrict__ fw,
                         float* __restrict__ ob, long o_ts, long o_es, int N)
{
    int wid = (int)(((long)blockIdx.x * blockDim.x + threadIdx.x) >> 6);
    int lane = threadIdx.x & 63;
    int total = NB * N * NCLS;
    if (wid >= total) return;
    int cls = wid % NCLS; int r = wid / NCLS;
    int n = r % N; int b = r / N;
    const float* a5 = a5b + (long)b * a_ts + (long)n * a_es;
    const float* g  = gb  + (long)b * g_ts + (long)n * g_es;
    const float* W  = fw + (long)b * PT + OFF_WO + (long)cls * FEAT;
    float acc = 0.f;
    for (int m = lane; m < FEAT; m += 64) acc += W[m] * a5[m] * g[m];
    for (int off = 32; off; off >>= 1) acc += __shfl_down(acc, off, 64);
    if (lane == 0)
        ob[(long)b * o_ts + (long)n * o_es + cls] = acc + fw[(long)b * PT + OFF_BO + cls];
}

// ---------------- inner softmax -> dlogit ----------------
__global__ void softmax_dlogit(const float* __restrict__ logi, const int* __restrict__ ty, int t,
                               float* __restrict__ dlog)
{
    __shared__ float red[128];
    int b = blockIdx.x, tid = threadIdx.x;
    const float* lo = logi + b * NCLS;
    float v = (tid < NCLS) ? lo[tid] : -1e30f;
    red[tid] = v; __syncthreads();
    for (int s2 = 64; s2; s2 >>= 1) { if (tid < s2) red[tid] = fmaxf(red[tid], red[tid + s2]); __syncthreads(); }
    float mx = red[0]; __syncthreads();
    float e = (tid < NCLS) ? expf(v - mx) : 0.f;
    red[tid] = e; __syncthreads();
    for (int s2 = 64; s2; s2 >>= 1) { if (tid < s2) red[tid] += red[tid + s2]; __syncthreads(); }
    float sum = red[0];
    if (tid < NCLS) {
        int y = ty[b * NT + t];
        dlog[b * NCLS + tid] = e / sum - (tid == y ? 1.f : 0.f);
    }
}

// ---------------- head backward: dz5 ----------------
__global__ void head_bwd_dz5(const float* __restrict__ fw, const float* __restrict__ dlog,
                             const float* __restrict__ ain, const float* __restrict__ gb, long g_ts,
                             float* __restrict__ dz)
{
    int idx = blockIdx.x * blockDim.x + threadIdx.x;
    if (idx >= NB * FEAT) return;
    int m = idx % FEAT, b = idx / FEAT;
    const float* W = fw + (long)b * PT + OFF_WO;
    float df = 0.f;
    for (int c = 0; c < NCLS; ++c) df += W[(long)c * FEAT + m] * dlog[b * NCLS + c];
    float a = ain[(long)b * ATOT + A5 + m];
    dz[(long)b * ATOT + A5 + m] = (a > 0.f) ? df * gb[(long)b * g_ts + m] : 0.f;
}

// ---------------- head update ----------------
__global__ void head_update(float* __restrict__ fw, const float* __restrict__ dlog,
                            const float* __restrict__ ain, const float* __restrict__ gb, long g_ts,
                            const float* __restrict__ loglr)
{
    long idx = (long)blockIdx.x * blockDim.x + threadIdx.x;
    long total = (long)NB * NCLS * FEAT;
    if (idx >= total) return;
    int m = (int)(idx % FEAT); long r = idx / FEAT;
    int c = (int)(r % NCLS); int b = (int)(r / NCLS);
    float lr = expf(loglr[0]);
    float f = ain[(long)b * ATOT + A5 + m] * gb[(long)b * g_ts + m];
    float dl = dlog[b * NCLS + c];
    fw[(long)b * PT + OFF_WO + (long)c * FEAT + m] -= lr * dl * f;
    if (m == 0) fw[(long)b * PT + OFF_BO + c] -= lr * dl;
}

// ---------------- conv backward dX (stride-2, parity taps, LDS weights) — r9 exact (kept for L1) ----------------
template<int IC,int IH,int IW,int OC,int OH,int OW,int ICG,int BLK>
__global__ __launch_bounds__(BLK) void conv_bwd_dx2(
    const float* __restrict__ dzbuf, int dz_off,
    const float* __restrict__ fw, int woff,
    const float* __restrict__ ain, int ain_off,
    float* __restrict__ dzin, int dzin_off)
{
    constexpr int IHW = IH*IW, OHW = OH*OW, NICG = IC/ICG, PB = IHW/BLK;
    __shared__ float wlds[OC*9*ICG];
    int bi = blockIdx.x;
    int pb  = bi % PB;
    int icg = (bi / PB) % NICG;
    int b   = bi / (PB * NICG);
    int ic0 = icg * ICG;
    const float* fwp = fw + (long)b * PT + woff;
    for (int i = threadIdx.x; i < OC*9*ICG; i += BLK) {
        int g = i % ICG; int rem = i / ICG; int k = rem % 9; int oc = rem / 9;
        wlds[i] = fwp[((long)oc * IC + ic0 + g) * 9 + k];
    }
    __syncthreads();

    int pix = pb * BLK + threadIdx.x;
    int ih = pix / IW, iw = pix % IW;
    int kh0 = (ih + 1) & 1, kw0 = (iw + 1) & 1;
    int ohA = (ih + 1 - kh0) >> 1, owA = (iw + 1 - kw0) >> 1;
    float mhA = (ohA < OH) ? 1.f : 0.f;   float mhB = (kh0 == 0) ? 1.f : 0.f;
    float mwA = (owA < OW) ? 1.f : 0.f;   float mwB = (kw0 == 0) ? 1.f : 0.f;
    int ohB = ohA - 1, owB = owA - 1;
    int ohAc = (ohA < OH) ? ohA : 0;  int owAc = (owA < OW) ? owA : 0;
    int ohBc = (ohB >= 0) ? ohB : 0;  int owBc = (owB >= 0) ? owB : 0;

    int oAA = ohAc*OW + owAc; float mAA = mhA*mwA; int kAA = kh0*3 + kw0;
    int oAB = ohAc*OW + owBc; float mAB = mhA*mwB; int kAB = kh0*3 + kw0 + 2;
    int oBA = ohBc*OW + owAc; float mBA = mhB*mwA; int kBA = (kh0+2)*3 + kw0;
    int oBB = ohBc*OW + owBc; float mBB = mhB*mwB; int kBB = (kh0+2)*3 + kw0 + 2;

    const float* dzp = dzbuf + (long)b * ATOT + dz_off;
    float acc[ICG];
    #pragma unroll
    for (int g = 0; g < ICG; ++g) acc[g] = 0.f;

    for (int oc = 0; oc < OC; ++oc) {
        const float* dzo = dzp + oc * OHW;
        float dAA = dzo[oAA] * mAA;
        float dAB = dzo[oAB] * mAB;
        float dBA = dzo[oBA] * mBA;
        float dBB = dzo[oBB] * mBB;
        const float* w = wlds + oc * 9 * ICG;
        #pragma unroll
        for (int g = 0; g < ICG; ++g)
            acc[g] += dAA * w[kAA*ICG+g] + dAB * w[kAB*ICG+g]
                    + dBA * w[kBA*ICG+g] + dBB * w[kBB*ICG+g];
    }
    #pragma unroll
    for (int g = 0; g < ICG; ++g) {
        long p = (long)b * ATOT + (long)(ic0 + g) * IHW + pix;
        float a = ain[p + ain_off];
        dzin[p + dzin_off] = (a > 0.f) ? acc[g] : 0.f;
    }
}

// ---------------- r19: OC-split conv backward dX (deep layers) ----------------
template<int IC,int IH,int IW,int OC,int OH,int OW,int ICG,int BLK,int KOS>
__global__ __launch_bounds__(BLK) void conv_bwd_dx2k(
    const float* __restrict__ dzbuf, int dz_off,
    const float* __restrict__ fw, int woff,
    float* __restrict__ pbuf)
{
    constexpr int IHW = IH*IW, OHW = OH*OW, NICG = IC/ICG, PB = IHW/BLK;
    constexpr int OCC = OC/KOS;
    __shared__ float wlds[OCC*9*ICG];
    int bi = blockIdx.x;
    int pb  = bi % PB;
    int icg = (bi / PB) % NICG;
    int kos = (bi / (PB * NICG)) % KOS;
    int b   = bi / (PB * NICG * KOS);
    int ic0 = icg * ICG;
    int ocb = kos * OCC;
    const float* fwp = fw + (long)b * PT + woff;
    for (int i = threadIdx.x; i < OCC*9*ICG; i += BLK) {
        int g = i % ICG; int rem = i / ICG; int k = rem % 9; int ocl = rem / 9;
        wlds[i] = fwp[((long)(ocb + ocl) * IC + ic0 + g) * 9 + k];
    }
    __syncthreads();

    int pix = pb * BLK + threadIdx.x;
    int ih = pix / IW, iw = pix % IW;
    int kh0 = (ih + 1) & 1, kw0 = (iw + 1) & 1;
    int ohA = (ih + 1 - kh0) >> 1, owA = (iw + 1 - kw0) >> 1;
    float mhA = (ohA < OH) ? 1.f : 0.f;   float mhB = (kh0 == 0) ? 1.f : 0.f;
    float mwA = (owA < OW) ? 1.f : 0.f;   float mwB = (kw0 == 0) ? 1.f : 0.f;
    int ohB = ohA - 1, owB = owA - 1;
    int ohAc = (ohA < OH) ? ohA : 0;  int owAc = (owA < OW) ? owA : 0;
    int ohBc = (ohB >= 0) ? ohB : 0;  int owBc = (owB >= 0) ? owB : 0;

    int oAA = ohAc*OW + owAc; float mAA = mhA*mwA; int kAA = kh0*3 + kw0;
    int oAB = ohAc*OW + owBc; float mAB = mhA*mwB; int kAB = kh0*3 + kw0 + 2;
    int oBA = ohBc*OW + owAc; float mBA = mhB*mwA; int kBA = (kh0+2)*3 + kw0;
    int oBB = ohBc*OW + owBc; float mBB = mhB*mwB; int kBB = (kh0+2)*3 + kw0 + 2;

    const float* dzp = dzbuf + (long)b * ATOT + dz_off;
    float acc[ICG];
    #pragma unroll
    for (int g = 0; g < ICG; ++g) acc[g] = 0.f;

    for (int ocl = 0; ocl < OCC; ++ocl) {
        const float* dzo = dzp + (ocb + ocl) * OHW;
        float dAA = dzo[oAA] * mAA;
        float dAB = dzo[oAB] * mAB;
        float dBA = dzo[oBA] * mBA;
        float dBB = dzo[oBB] * mBB;
        const float* w = wlds + ocl * 9 * ICG;
        #pragma unroll
        for (int g = 0; g < ICG; ++g)
            acc[g] += dAA * w[kAA*ICG+g] + dAB * w[kAB*ICG+g]
                    + dBA * w[kBA*ICG+g] + dBB * w[kBB*ICG+g];
    }
    float* pp = pbuf + ((long)kos * NB + b) * ((long)IC * IHW);
    #pragma unroll
    for (int g = 0; g < ICG; ++g)
        pp[(long)(ic0 + g) * IHW + pix] = acc[g];
}

// r19: sum KOS dx partials + ReLU mask -> dzin
template<int KOS>
__global__ __launch_bounds__(256) void ksum_dx(
    const float* __restrict__ pbuf, const float* __restrict__ ain, int ain_off,
    float* __restrict__ dzin, int dzin_off, long ichw)
{
    long idx = (long)blockIdx.x * 256 + threadIdx.x;
    long total = (long)NB * ichw;
    if (idx >= total) return;
    int b = (int)(idx / ichw);
    long rem = idx % ichw;
    float s = 0.f;
    #pragma unroll
    for (int kos = 0; kos < KOS; ++kos)
        s += pbuf[((long)kos * NB + b) * ichw + rem];
    long p = (long)b * ATOT + rem;
    float a = ain[p + ain_off];
    dzin[p + dzin_off] = (a > 0.f) ? s : 0.f;
}

// ---------------- conv backward dW+db: one wave per (b, oc, ic) — kept for L1 ----------------
template<int IC,int IH,int IW,int OC,int OH,int OW,int S>
__global__ __launch_bounds__(64) void conv_bwd_dw2(
    float* __restrict__ fw, int woff, int boff,
    const float* __restrict__ dzbuf, int dz_off,
    const float* __restrict__ xb, long x_ts,
    const float* __restrict__ loglr)
{
    constexpr int OHW = OH*OW;
    int bi = blockIdx.x;
    int ic = bi % IC; int oc = (bi / IC) % OC; int b = bi / (IC * OC);
    int lane = threadIdx.x;
    const float* dzp = dzbuf + (long)b * ATOT + dz_off + (long)oc * OHW;
    const float* xp  = xb + (long)b * x_ts + (long)ic * IH * IW;

    float acc[10];
    #pragma unroll
    for (int k = 0; k < 10; ++k) acc[k] = 0.f;

    for (int pos = lane; pos < OHW; pos += 64) {
        float dzv = dzp[pos];
        int oh = pos / OW, ow = pos % OW;
        int ihb = oh * S - 1, iwb = ow * S - 1;
        acc[9] += dzv;
        #pragma unroll
        for (int kh = 0; kh < 3; ++kh) {
            int ih = ihb + kh;
            bool hv = ((unsigned)ih < (unsigned)IH);
            #pragma unroll
            for (int kw = 0; kw < 3; ++kw) {
                int iw = iwb + kw;
                float xv = (hv && (unsigned)iw < (unsigned)IW) ? xp[ih * IW + iw] : 0.f;
                acc[kh*3+kw] += dzv * xv;
            }
        }
    }
    #pragma unroll
    for (int k = 0; k < 10; ++k)
        for (int off = 32; off; off >>= 1) acc[k] += __shfl_down(acc[k], off, 64);

    if (lane == 0) {
        float lr = expf(loglr[0]);
        float* wp = fw + (long)b * PT + woff + ((long)oc * IC + ic) * 9;
        #pragma unroll
        for (int k = 0; k < 9; ++k) wp[k] -= lr * acc[k];
        if (ic == 0) fw[(long)b * PT + boff + oc] -= lr * acc[9];
    }
}

// ---------------- r16: spatially-split dW (L0) + finalize ----------------
template<int IC,int IH,int IW,int OC,int OH,int OW,int S,int NSP>
__global__ __launch_bounds__(64) void conv_bwd_dw2s(
    float* __restrict__ pbuf,
    const float* __restrict__ dzbuf, int dz_off,
    const float* __restrict__ xb, long x_ts)
{
    constexpr int OHW = OH*OW, CH = OHW/NSP;
    int bi = blockIdx.x;
    int sp = bi % NSP; int ic = (bi / NSP) % IC;
    int oc = (bi / (NSP*IC)) % OC; int b = bi / (NSP*IC*OC);
    int lane = threadIdx.x;
    const float* dzp = dzbuf + (long)b * ATOT + dz_off + (long)oc * OHW;
    const float* xp  = xb + (long)b * x_ts + (long)ic * IH * IW;

    float acc[10];
    #pragma unroll
    for (int k = 0; k < 10; ++k) acc[k] = 0.f;

    for (int pos = sp*CH + lane; pos < sp*CH + CH; pos += 64) {
        float dzv = dzp[pos];
        int oh = pos / OW, ow = pos % OW;
        int ihb = oh * S - 1, iwb = ow * S - 1;
        acc[9] += dzv;
        #pragma unroll
        for (int kh = 0; kh < 3; ++kh) {
            int ih = ihb + kh;
            bool hv = ((unsigned)ih < (unsigned)IH);
            #pragma unroll
            for (int kw = 0; kw < 3; ++kw) {
                int iw = iwb + kw;
                float xv = (hv && (unsigned)iw < (unsigned)IW) ? xp[ih * IW + iw] : 0.f;
                acc[kh*3+kw] += dzv * xv;
            }
        }
    }
    #pragma unroll
    for (int k = 0; k < 10; ++k)
        for (int off = 32; off; off >>= 1) acc[k] += __shfl_down(acc[k], off, 64);

    if (lane == 0) {
        float* pp = pbuf + ((((long)sp*NB + b)*OC + oc)*IC + ic)*10;
        #pragma unroll
        for (int k = 0; k < 10; ++k) pp[k] = acc[k];
    }
}

template<int NSP>
__global__ void dw_finalize(const float* __restrict__ pbuf, float* __restrict__ fw,
                            int woff, int boff, const float* __restrict__ loglr,
                            int OC, int IC)
{
    int idx = blockIdx.x * blockDim.x + threadIdx.x;
    int total = NB * OC * IC * 10;
    if (idx >= total) return;
    int k = idx % 10; int r = idx / 10;
    int ic = r % IC; r /= IC;
    int oc = r % OC; int b = r / OC;
    float s = 0.f;
    #pragma unroll
    for (int sp = 0; sp < NSP; ++sp)
        s += pbuf[((((long)sp*NB + b)*OC + oc)*IC + ic)*10 + k];
    float lr = expf(loglr[0]);
    if (k < 9)
        fw[(long)b*PT + woff + ((long)oc*IC + ic)*9 + k] -= lr * s;
    else if (ic == 0)
        fw[(long)b*PT + boff + oc] -= lr * s;
}

// ---------------- final loss / eval ----------------
__global__ void final_loss_eval(const float* __restrict__ logit_base,
                                const int* __restrict__ test_y,
                                float* __restrict__ out, int l0, int Lc)
{
    int idx = blockIdx.x * blockDim.x + threadIdx.x;
    if (idx >= NB * Lc) return;
    int n = idx % Lc, b = idx / Lc;
    int l = l0 + n;
    const float* lo = logit_base + ((long)b * NL + l) * NCLS;
    float mx = -1e30f; int am = 0;
    for (int c = 0; c < NCLS; ++c) { float v = lo[c]; if (v > mx) { mx = v; am = c; } }
    float se = 0.f;
    for (int c = 0; c < NCLS; ++c) se += expf(lo[c] - mx);
    int y = test_y[b * NL + l];
    out[b * NL + l] = -(lo[y] - mx - logf(se));
    out[129 + b * NL + l] = (am == y) ? 1.f : 0.f;
}

__global__ void write_lr(const float* __restrict__ loglr, float* __restrict__ out)
{
    if (threadIdx.x == 0 && blockIdx.x == 0) out[128] = expf(loglr[0]);
}

// ---------------- host orchestration ----------------
extern "C" void kernel_launch(void* const* d_in, const int* in_sizes, int n_in,
                              void* d_out, int out_size, void* d_ws, size_t ws_size,
                              hipStream_t stream)
{
    const float* loglr      = (const float*)d_in[12];
    const float* train_x    = (const float*)d_in[13];
    const float* test_x     = (const float*)d_in[14];
    const float* train_gate = (const float*)d_in[15];
    const float* test_gate  = (const float*)d_in[16];
    const int*   train_y    = (const int*)d_in[17];
    const int*   test_y     = (const int*)d_in[18];
    float* out = (float*)d_out;

    const long base = (long)NB*PT + 2L*NB*ATOT + 2L*NB*NCLS;
    int LCr = 4;
    if (ws_size >= (size_t)(base + 16L*1572864) * 4) LCr = 16;
    else if (ws_size >= (size_t)(base + 8L*1572864) * 4) LCr = 8;

    float* ws   = (float*)d_ws;
    float* FWp  = ws;
    float* AINp = FWp  + (long)NB * PT;
    float* DZp  = AINp + (long)NB * ATOT;
    float* LOGIp= DZp  + (long)NB * ATOT;
    float* DLOGp= LOGIp + NB * NCLS;
    float* TAp  = DLOGp + NB * NCLS;
    float* TBp  = TAp + (long)NB * LCr * 131072;

    // train-phase scratch (TAp is free until the test phase; min TAp = 4.19M floats at LCr=4)
    float* P3t = TAp;                       // 2*NB*256*64  = 262144
    float* P4t = TAp + 262144;              // 4*NB*256*16  = 131072
    float* PW0 = TAp + 262144 + 131072;     // 8*NB*32*3*10 =  61440
    float* PDX = TAp + 458752;              // dx partials, max 4*NB*32768 = 1,048,576 -> ends 1.51M

    Params12 ps;
    for (int j = 0; j < 12; ++j) ps.p[j] = (const float*)d_in[j];
    {
        long tot = (long)NB * PT;
        bcast_kernel<<<(int)((tot + 255) / 256), 256, 0, stream>>>(ps, FWp);
    }

    for (int t = 0; t < NT; ++t) {
        // ---- forward convs (train) ----
        conv_fwd_u<3,64,64,32,64,64,1,3,256><<<4096, 256, 0, stream>>>(
            train_x + (long)t * CHW, (long)NT * CHW, FWp, OFF_W0, OFF_B0, AINp + A1, (long)ATOT);
        conv_fwd_u<32,64,64,64,32,32,2,4,256><<<2048, 256, 0, stream>>>(
            AINp + A1, (long)ATOT, FWp, OFF_W1, OFF_B1, AINp + A2, (long)ATOT);
        conv_fwd_u<64,32,32,128,16,16,2,4,256><<<1024, 256, 0, stream>>>(
            AINp + A2, (long)ATOT, FWp, OFF_W2, OFF_B2, AINp + A3, (long)ATOT);
        // L3: KS=2, oc-uniform scalar weights -> 4096 waves (r24: unswizzled)
        conv_fwd_us<128,16,16,256,8,8,2,4, 2><<<NB*2*256, 64, 0, stream>>>(
            AINp + A3, (long)ATOT, FWp, OFF_W3, P3t);
        ksum_relu<2><<<(NB*256*64 + 255) / 256, 256, 0, stream>>>(
            P3t, FWp, OFF_B3, AINp + A4, (long)ATOT, 1, 256, 64);
        // L4: KS=4 -> 2048 waves (r24: unswizzled)
        conv_fwd_uks<256,8,8,256,4,4,2,8,64, 4><<<2048, 64, 0, stream>>>(
            AINp + A4, (long)ATOT, FWp, OFF_W4, P4t);
        ksum_relu<4><<<(NB*256*16 + 255) / 256, 256, 0, stream>>>(
            P4t, FWp, OFF_B4, AINp + A5, (long)ATOT, 1, 256, 16);

        {
            long waves = (long)NB * NCLS;
            head_fwd<<<(int)((waves * 64 + 255) / 256), 256, 0, stream>>>(
                AINp + A5, (long)ATOT, 0,
                train_gate + (long)t * FEAT, (long)NT * FEAT, 0,
                FWp, LOGIp, (long)NCLS, 0, 1);
        }
        softmax_dlogit<<<NB, 128, 0, stream>>>(LOGIp, train_y, t, DLOGp);
        head_bwd_dz5<<<(NB * FEAT + 255) / 256, 256, 0, stream>>>(
            FWp, DLOGp, AINp, train_gate + (long)t * FEAT, (long)NT * FEAT, DZp);
        {
            long tot = (long)NB * NCLS * FEAT;
            head_update<<<(int)((tot + 255) / 256), 256, 0, stream>>>(
                FWp, DLOGp, AINp, train_gate + (long)t * FEAT, (long)NT * FEAT, loglr);
        }

        // ---- backward chain (r19 structure, FROZEN) ----
        conv_bwd_dx2k<256,8,8,256,4,4,2,64, 4><<<4096, 64, 0, stream>>>(
            DZp, A5, FWp, OFF_W4, PDX);
        ksum_dx<4><<<(int)(((long)NB*16384 + 255) / 256), 256, 0, stream>>>(
            PDX, AINp, A4, DZp, A4, 16384);
        conv_bwd_dwg<256,8,8,256,4,4,2, 64,8,2, 4><<<1024, 256, 0, stream>>>(
            FWp, OFF_W4, OFF_B4, DZp, A5, AINp + A4, (long)ATOT, loglr);

        conv_bwd_dx2k<128,16,16,256,8,8,4,256, 4><<<1024, 256, 0, stream>>>(
            DZp, A4, FWp, OFF_W3, PDX);
        ksum_dx<4><<<(int)(((long)NB*32768 + 255) / 256), 256, 0, stream>>>(
            PDX, AINp, A3, DZp, A3, 32768);
        conv_bwd_dwg<128,16,16,256,8,8,2, 64,8,2, 8><<<512, 256, 0, stream>>>(
            FWp, OFF_W3, OFF_B3, DZp, A4, AINp + A3, (long)ATOT, loglr);

        conv_bwd_dx2k<64,32,32,128,16,16,4,256, 2><<<1024, 256, 0, stream>>>(
            DZp, A3, FWp, OFF_W2, PDX);
        ksum_dx<2><<<(int)(((long)NB*65536 + 255) / 256), 256, 0, stream>>>(
            PDX, AINp, A2, DZp, A2, 65536);
        conv_bwd_dwg<64,32,32,128,16,16,2, 32,8,1, 4><<<256, 256, 0, stream>>>(
            FWp, OFF_W2, OFF_B2, DZp, A3, AINp + A2, (long)ATOT, loglr);

        conv_bwd_dx2<32,64,64,64,32,32,4,256><<<8*8*16, 256, 0, stream>>>(
            DZp, A2, FWp, OFF_W1, AINp, A1, DZp, A1);
        conv_bwd_dw2<32,64,64,64,32,32,2><<<8*64*32, 64, 0, stream>>>(
            FWp, OFF_W1, OFF_B1, DZp, A2, AINp + A1, (long)ATOT, loglr);
        conv_bwd_dw2s<3,64,64,32,64,64,1, 8><<<8*32*3*8, 64, 0, stream>>>(
            PW0, DZp, A1, train_x + (long)t * CHW, (long)NT * CHW);
        dw_finalize<8><<<(NB*32*3*10 + 255) / 256, 256, 0, stream>>>(
            PW0, FWp, OFF_W0, OFF_B0, loglr, 32, 3);
    }

    // 3) test forward
    if (LCr == 16) {
        conv_fwd2<3,64,64,32,64,64,1, 32,1,3><<<NB*16*16, 256, 0, stream>>>(
            test_x, (long)NL * CHW, CHW,
            FWp, OFF_W0, OFF_B0, TAp, 16L * 131072, 16);

        // r23 gx (XCD swizzle + phase-split LDS), FROZEN
        // L1 (32->64): TOCP=16, grid = 2048
        conv_fwd_gx<32,64,64, 64,32,32, 2, 1,2,8, 1, 16, 16><<<2048, 256, 0, stream>>>(
            TAp, 16L*131072, 131072, FWp, OFF_W1, OFF_B1, TBp, 16L*65536, nullptr);
        // L2 (64->128): TOCP=8 -> NOCG=4, grid = 2048
        conv_fwd_gx<64,32,32, 128,16,16, 2, 1,4,8, 1, 16, 8><<<2048, 256, 0, stream>>>(
            TBp, 16L*65536, 65536, FWp, OFF_W2, OFF_B2, TAp, 16L*32768, nullptr);
        // L3 (128->256): KS=4 partials, TOCP=16, grid = 2048
        {
            float* P3 = TAp + 4194304;   // 4 * 8*16*256*64 = 8,388,608 -> ends 12.58M < 16.78M
            conv_fwd_gx<128,16,16, 256,8,8, 2, 1,8,8, 4, 16, 16><<<2048, 256, 0, stream>>>(
                TAp, 16L*32768, 32768, FWp, OFF_W3, 0, nullptr, 0, P3);
            ksum_relu<4><<<(int)(((long)NB*16*256*64 + 255) / 256), 256, 0, stream>>>(
                P3, FWp, OFF_B3, TBp, 16L * 16384, 16, 256, 64);
        }
        // L4 (256->256): TOCP=8 -> NOCG=8, KS=8, grid = 2048
        {
            float* P4 = TBp + 2097152;   // 8 * 8*16*256*16 = 4,194,304 -> ends 6.29M < 8.39M
            conv_fwd_gx<256,8,8, 256,4,4, 2, 4,4,8, 8, 16, 8><<<2048, 256, 0, stream>>>(
                TBp, 16L*16384, 16384, FWp, OFF_W4, 0, nullptr, 0, P4);
            ksum_relu<8><<<(int)(((long)NB*16*256*16 + 255) / 256), 256, 0, stream>>>(
                P4, FWp, OFF_B4, TAp, 16L * 4096, 16, 256, 16);
        }
        {
            long waves = (long)NB * 16 * NCLS;
            head_fwd<<<(int)((waves * 64 + 255) / 256), 256, 0, stream>>>(
                TAp, 16L * FEAT, FEAT,
                test_gate, (long)NL * FEAT, FEAT,
                FWp, out + 257, (long)NL * NCLS, NCLS, 16);
        }
    } else {
        for (int c = 0; c < NL / LCr; ++c) {
            int l0 = c * LCr;
            conv_fwd2<3,64,64,32,64,64,1, 32,1,3><<<NB*LCr*16, 256, 0, stream>>>(
                test_x + (long)l0 * CHW, (long)NL * CHW, CHW,
                FWp, OFF_W0, OFF_B0, TAp, (long)LCr * 131072, LCr);
            conv_fwd2<32,64,64,64,32,32,2, 16,1,8><<<NB*LCr*16, 256, 0, stream>>>(
                TAp, (long)LCr * 131072, 131072,
                FWp, OFF_W1, OFF_B1, TBp, (long)LCr * 65536, LCr);
            conv_fwd2<64,32,32,128,16,16,2, 16,1,8><<<NB*LCr*8, 256, 0, stream>>>(
                TBp, (long)LCr * 65536, 65536,
                FWp, OFF_W2, OFF_B2, TAp, (long)LCr * 32768, LCr);
            conv_fwd2<128,16,16,256,8,8,2, 8,4,8><<<NB*LCr*8, 256, 0, stream>>>(
                TAp, (long)LCr * 32768, 32768,
                FWp, OFF_W3, OFF_B3, TBp, (long)LCr * 16384, LCr);
            conv_fwd2<256,8,8,256,4,4,2, 4,16,8><<<NB*LCr*4, 256, 0, stream>>>(
                TBp, (long)LCr * 16384, 16384,
                FWp, OFF_W4, OFF_B4, TAp, (long)LCr * 4096, LCr);
            {
                long waves = (long)NB * LCr * NCLS;
                head_fwd<<<(int)((waves * 64 + 255) / 256), 256, 0, stream>>>(
                    TAp, (long)LCr * FEAT, FEAT,
                    test_gate + (long)l0 * FEAT, (long)NL * FEAT, FEAT,
                    FWp, out + 257 + (long)l0 * NCLS, (long)NL * NCLS, NCLS, LCr);
            }
        }
    }
    final_loss_eval<<<(NB * NL + 255) / 256, 256, 0, stream>>>(
        out + 257, test_y, out, 0, NL);
    write_lr<<<1, 1, 0, stream>>>(loglr, out);
}